// Round 3
// baseline (2807.719 us; speedup 1.0000x reference)
//
#include <hip/hip_runtime.h>
#include <hip/hip_bf16.h>
#include <cstdint>
#include <cstddef>

// Problem constants (B,S,D,H fixed by the reference)
constexpr int Bc  = 4;
constexpr int Sc  = 2048;
constexpr int Dc  = 1024;
constexpr int Hc  = 16;
constexpr int DKc = 64;
constexpr int Mtot = Bc * Sc;              // 8192 rows
constexpr float INFTY = 1000000.0f;

// ---------------------------------------------------------------------------
// Kernel 0: normalize the padding mask to int32[8192] regardless of shipped
// dtype (numpy bool_ -> uint8, or int32/int64/f32). Deterministic: input fixed.
// ---------------------------------------------------------------------------
__global__ __launch_bounds__(256) void mask_norm(const void* __restrict__ mraw,
                                                 int* __restrict__ mi) {
    __shared__ int fF32, fU8, fI32;
    if (threadIdx.x == 0) { fF32 = 0; fU8 = 0; fI32 = 0; }
    __syncthreads();
    const unsigned char* mb = (const unsigned char*)mraw;
    int aF = 0, a1 = 0, a4 = 0;
    for (int i = threadIdx.x; i < Mtot; i += 256) {
        unsigned char v = mb[i];
        if ((i & 3) == 3 && v == 0x3F) aF = 1;
        if (v) {
            if (i & 3) a1 = 1;
            else if (i & 7) a4 = 1;
        }
    }
    if (aF) fF32 = 1;
    if (a1) fU8 = 1;
    if (a4) fI32 = 1;
    __syncthreads();
    if (fF32) {
        const float* mf = (const float*)mraw;
        for (int s = threadIdx.x; s < Mtot; s += 256) mi[s] = (mf[s] != 0.0f);
    } else if (fU8) {
        for (int s = threadIdx.x; s < Mtot; s += 256) mi[s] = (mb[s] != 0);
    } else if (fI32) {
        const int* m32 = (const int*)mraw;
        for (int s = threadIdx.x; s < Mtot; s += 256) mi[s] = (m32[s] != 0);
    } else {
        const long long* m64 = (const long long*)mraw;
        for (int s = threadIdx.x; s < Mtot; s += 256) mi[s] = (m64[s] != 0);
    }
}

// ---------------------------------------------------------------------------
// Kernel 1: f32 tiled GEMM P = A @ W with fused head-split epilogue.
// Reference: head h = column (dk*H + h); Hd[b,h,s,dk] = P[b*S+s, dk*16+h].
// ---------------------------------------------------------------------------
__global__ __launch_bounds__(256) void gemm_proj(const float* __restrict__ A,
                                                 const float* __restrict__ W,
                                                 float* __restrict__ Hd) {
    __shared__ float As[64][20];
    __shared__ float Bs[16][68];
    const int t  = threadIdx.x;
    const int tx = t & 15, ty = t >> 4;
    const int m0 = blockIdx.y * 64, n0 = blockIdx.x * 64;
    float acc[4][4] = {};
    for (int k0 = 0; k0 < Dc; k0 += 16) {
        {
            const int r = t >> 2, kq = (t & 3) * 4;
            float4 av = *reinterpret_cast<const float4*>(&A[(size_t)(m0 + r) * Dc + k0 + kq]);
            *reinterpret_cast<float4*>(&As[r][kq]) = av;
            const int kr = t >> 4, nc = (t & 15) * 4;
            float4 bv = *reinterpret_cast<const float4*>(&W[(size_t)(k0 + kr) * Dc + n0 + nc]);
            *reinterpret_cast<float4*>(&Bs[kr][nc]) = bv;
        }
        __syncthreads();
        #pragma unroll
        for (int kk = 0; kk < 16; ++kk) {
            float a[4], b[4];
            #pragma unroll
            for (int mi = 0; mi < 4; ++mi) a[mi] = As[ty * 4 + mi][kk];
            #pragma unroll
            for (int ni = 0; ni < 4; ++ni) b[ni] = Bs[kk][tx * 4 + ni];
            #pragma unroll
            for (int mi = 0; mi < 4; ++mi)
                #pragma unroll
                for (int ni = 0; ni < 4; ++ni)
                    acc[mi][ni] += a[mi] * b[ni];
        }
        __syncthreads();
    }
    #pragma unroll
    for (int mq = 0; mq < 4; ++mq) {
        const int gm = m0 + ty * 4 + mq;
        const int b = gm >> 11, s = gm & 2047;
        #pragma unroll
        for (int ni = 0; ni < 4; ++ni) {
            const int n  = n0 + tx * 4 + ni;
            const int h  = n & 15, dk = n >> 4;     // column = dk*16 + h
            Hd[((size_t)(b * Hc + h) * Sc + s) * DKc + dk] = acc[mq][ni];
        }
    }
}

// ---------------------------------------------------------------------------
// Kernel 2: flash-style f32 attention. 256 thr, 32 queries/block, key tiles
// of 64. Grid (S/32, B*H). att[b,s, h*64+dk] output (ready for @WO).
// ---------------------------------------------------------------------------
__global__ __launch_bounds__(256) void attn(const float* __restrict__ Qh,
                                            const float* __restrict__ Kh,
                                            const float* __restrict__ Vh,
                                            const int*   __restrict__ mask,
                                            float* __restrict__ att) {
    constexpr int TQ = 32, TK = 64;
    const int bh = blockIdx.y;                 // b*H + h
    const int b = bh >> 4, h = bh & 15;
    const int q0 = blockIdx.x * TQ;
    const float* Qb = Qh + ((size_t)bh * Sc + q0) * DKc;
    const float* Kb = Kh + (size_t)bh * Sc * DKc;
    const float* Vb = Vh + (size_t)bh * Sc * DKc;
    const int*   mb = mask + b * Sc;

    __shared__ float Ks[TK][DKc + 4];
    __shared__ float Vs[TK][DKc + 4];
    __shared__ float Ps[TQ][TK + 1];
    __shared__ float rowm[TQ], rowl[TQ], rowr[TQ];
    __shared__ int   mk[TK];

    const int t  = threadIdx.x;
    const int i  = t >> 3;                     // query row 0..31 (8 thr/row)
    const int ju = t & 7;                      // key cols ju, ju+8, ..., ju+56
    const int dchunk = (t & 7) * 8;            // 8 dims of PV accumulator

    float q[DKc];
    #pragma unroll
    for (int d = 0; d < DKc; d += 4) {
        float4 v = *reinterpret_cast<const float4*>(&Qb[(size_t)i * DKc + d]);
        q[d] = v.x; q[d + 1] = v.y; q[d + 2] = v.z; q[d + 3] = v.w;
    }
    if (t < TQ) { rowm[t] = -1e30f; rowl[t] = 0.0f; }
    float acc[8] = {};

    for (int k0 = 0; k0 < Sc; k0 += TK) {
        #pragma unroll
        for (int l = 0; l < 4; ++l) {
            const int idx = t + l * 256;       // float4 index 0..1023
            const int r = idx >> 4, dq = (idx & 15) * 4;
            *reinterpret_cast<float4*>(&Ks[r][dq]) =
                *reinterpret_cast<const float4*>(&Kb[(size_t)(k0 + r) * DKc + dq]);
            *reinterpret_cast<float4*>(&Vs[r][dq]) =
                *reinterpret_cast<const float4*>(&Vb[(size_t)(k0 + r) * DKc + dq]);
        }
        if (t < TK) mk[t] = mb[k0 + t];
        __syncthreads();

        float sc[8] = {};
        #pragma unroll
        for (int d = 0; d < DKc; d += 4) {
            #pragma unroll
            for (int c = 0; c < 8; ++c) {
                float4 kv = *reinterpret_cast<const float4*>(&Ks[ju + 8 * c][d]);
                sc[c] += q[d] * kv.x + q[d + 1] * kv.y + q[d + 2] * kv.z + q[d + 3] * kv.w;
            }
        }
        #pragma unroll
        for (int c = 0; c < 8; ++c) Ps[i][ju + 8 * c] = sc[c];
        __syncthreads();

        if (t < TQ) {
            const float m_old = rowm[t], l_old = rowl[t];
            float mx = -1e30f;
            for (int j = 0; j < TK; ++j) {
                float v = Ps[t][j] * 0.125f - (mk[j] ? 0.0f : INFTY);
                Ps[t][j] = v;
                mx = fmaxf(mx, v);
            }
            const float m_new = fmaxf(m_old, mx);
            const float r = __expf(m_old - m_new);
            float sum = 0.0f;
            for (int j = 0; j < TK; ++j) {
                float p = __expf(Ps[t][j] - m_new);
                Ps[t][j] = p;
                sum += p;
            }
            rowm[t] = m_new; rowl[t] = l_old * r + sum; rowr[t] = r;
        }
        __syncthreads();

        const float r = rowr[i];
        #pragma unroll
        for (int c = 0; c < 8; ++c) acc[c] *= r;
        for (int j = 0; j < TK; ++j) {
            const float p = Ps[i][j];
            float4 v0 = *reinterpret_cast<const float4*>(&Vs[j][dchunk]);
            float4 v1 = *reinterpret_cast<const float4*>(&Vs[j][dchunk + 4]);
            acc[0] += p * v0.x; acc[1] += p * v0.y; acc[2] += p * v0.z; acc[3] += p * v0.w;
            acc[4] += p * v1.x; acc[5] += p * v1.y; acc[6] += p * v1.z; acc[7] += p * v1.w;
        }
        __syncthreads();
    }

    const float inv = 1.0f / rowl[i];
    const int s = q0 + i;
    float* dstp = att + (size_t)(b * Sc + s) * Dc + h * DKc + dchunk;
    #pragma unroll
    for (int c = 0; c < 8; ++c) dstp[c] = acc[c] * inv;
}

// ---------------------------------------------------------------------------
// Kernel 3: output GEMM + query-mask + abs + f32 store (reference output
// dtype is float32 — x and W are f32 throughout).
// ---------------------------------------------------------------------------
__global__ __launch_bounds__(256) void gemm_oproj(const float* __restrict__ A,
                                                  const float* __restrict__ W,
                                                  const int*   __restrict__ mask,
                                                  float* __restrict__ out) {
    __shared__ float As[64][20];
    __shared__ float Bs[16][68];
    const int t  = threadIdx.x;
    const int tx = t & 15, ty = t >> 4;
    const int m0 = blockIdx.y * 64, n0 = blockIdx.x * 64;
    float acc[4][4] = {};
    for (int k0 = 0; k0 < Dc; k0 += 16) {
        {
            const int r = t >> 2, kq = (t & 3) * 4;
            float4 av = *reinterpret_cast<const float4*>(&A[(size_t)(m0 + r) * Dc + k0 + kq]);
            *reinterpret_cast<float4*>(&As[r][kq]) = av;
            const int kr = t >> 4, nc = (t & 15) * 4;
            float4 bv = *reinterpret_cast<const float4*>(&W[(size_t)(k0 + kr) * Dc + n0 + nc]);
            *reinterpret_cast<float4*>(&Bs[kr][nc]) = bv;
        }
        __syncthreads();
        #pragma unroll
        for (int kk = 0; kk < 16; ++kk) {
            float a[4], b[4];
            #pragma unroll
            for (int mi = 0; mi < 4; ++mi) a[mi] = As[ty * 4 + mi][kk];
            #pragma unroll
            for (int ni = 0; ni < 4; ++ni) b[ni] = Bs[kk][tx * 4 + ni];
            #pragma unroll
            for (int mi = 0; mi < 4; ++mi)
                #pragma unroll
                for (int ni = 0; ni < 4; ++ni)
                    acc[mi][ni] += a[mi] * b[ni];
        }
        __syncthreads();
    }
    #pragma unroll
    for (int mq = 0; mq < 4; ++mq) {
        const int gm = m0 + ty * 4 + mq;
        const int mv = mask[gm];
        #pragma unroll
        for (int ni = 0; ni < 4; ++ni) {
            const float o = mv ? fabsf(acc[mq][ni]) : 0.0f;
            out[(size_t)gm * Dc + n0 + tx * 4 + ni] = o;
        }
    }
}

// ---------------------------------------------------------------------------
extern "C" void kernel_launch(void* const* d_in, const int* in_sizes, int n_in,
                              void* d_out, int out_size, void* d_ws, size_t ws_size,
                              hipStream_t stream) {
    const float* x    = (const float*)d_in[0];
    const void*  mraw = d_in[1];
    const float* WQ   = (const float*)d_in[2];
    const float* WK   = (const float*)d_in[3];
    const float* WV   = (const float*)d_in[4];
    const float* WO   = (const float*)d_in[5];
    float* out = (float*)d_out;

    // ws layout: mask_i (32 KB) | Qh | Kh | Vh | att   (4 x 33.55 MB f32)
    int*   mi   = (int*)d_ws;
    float* base = (float*)((char*)d_ws + 32768);
    const size_t SZ = (size_t)Mtot * Dc;
    float* Qh  = base;
    float* Kh  = base + SZ;
    float* Vh  = base + 2 * SZ;
    float* att = base + 3 * SZ;

    mask_norm<<<1, 256, 0, stream>>>(mraw, mi);

    const dim3 gGemm(Dc / 64, Mtot / 64);      // (16,128)
    gemm_proj<<<gGemm, 256, 0, stream>>>(x, WQ, Qh);
    gemm_proj<<<gGemm, 256, 0, stream>>>(x, WK, Kh);
    gemm_proj<<<gGemm, 256, 0, stream>>>(x, WV, Vh);

    attn<<<dim3(Sc / 32, Bc * Hc), 256, 0, stream>>>(Qh, Kh, Vh, mi, att);

    gemm_oproj<<<gGemm, 256, 0, stream>>>(att, WO, mi, out);
}

// Round 4
// 2234.787 us; speedup vs baseline: 1.2564x; 1.2564x over previous
//
#include <hip/hip_runtime.h>
#include <hip/hip_bf16.h>
#include <cstdint>
#include <cstddef>

// Problem constants (B,S,D,H fixed by the reference)
constexpr int Bc  = 4;
constexpr int Sc  = 2048;
constexpr int Dc  = 1024;
constexpr int Hc  = 16;
constexpr int DKc = 64;
constexpr int Mtot = Bc * Sc;              // 8192 rows
constexpr float INFTY = 1000000.0f;

// ---------------------------------------------------------------------------
// Kernel 0: normalize the padding mask to int32[8192] regardless of shipped
// dtype (numpy bool_ -> uint8, or int32/int64/f32). Deterministic: input fixed.
// ---------------------------------------------------------------------------
__global__ __launch_bounds__(256) void mask_norm(const void* __restrict__ mraw,
                                                 int* __restrict__ mi) {
    __shared__ int fF32, fU8, fI32;
    if (threadIdx.x == 0) { fF32 = 0; fU8 = 0; fI32 = 0; }
    __syncthreads();
    const unsigned char* mb = (const unsigned char*)mraw;
    int aF = 0, a1 = 0, a4 = 0;
    for (int i = threadIdx.x; i < Mtot; i += 256) {
        unsigned char v = mb[i];
        if ((i & 3) == 3 && v == 0x3F) aF = 1;
        if (v) {
            if (i & 3) a1 = 1;
            else if (i & 7) a4 = 1;
        }
    }
    if (aF) fF32 = 1;
    if (a1) fU8 = 1;
    if (a4) fI32 = 1;
    __syncthreads();
    if (fF32) {
        const float* mf = (const float*)mraw;
        for (int s = threadIdx.x; s < Mtot; s += 256) mi[s] = (mf[s] != 0.0f);
    } else if (fU8) {
        for (int s = threadIdx.x; s < Mtot; s += 256) mi[s] = (mb[s] != 0);
    } else if (fI32) {
        const int* m32 = (const int*)mraw;
        for (int s = threadIdx.x; s < Mtot; s += 256) mi[s] = (m32[s] != 0);
    } else {
        const long long* m64 = (const long long*)mraw;
        for (int s = threadIdx.x; s < Mtot; s += 256) mi[s] = (m64[s] != 0);
    }
}

// ---------------------------------------------------------------------------
// Kernel 1: f32 tiled GEMM P = A @ W with fused head-split epilogue.
// Reference: head h = column (dk*H + h); Hd[b,h,s,dk] = P[b*S+s, dk*16+h].
// ---------------------------------------------------------------------------
__global__ __launch_bounds__(256) void gemm_proj(const float* __restrict__ A,
                                                 const float* __restrict__ W,
                                                 float* __restrict__ Hd) {
    __shared__ float As[64][20];
    __shared__ float Bs[16][68];
    const int t  = threadIdx.x;
    const int tx = t & 15, ty = t >> 4;
    const int m0 = blockIdx.y * 64, n0 = blockIdx.x * 64;
    float acc[4][4] = {};
    for (int k0 = 0; k0 < Dc; k0 += 16) {
        {
            const int r = t >> 2, kq = (t & 3) * 4;
            float4 av = *reinterpret_cast<const float4*>(&A[(size_t)(m0 + r) * Dc + k0 + kq]);
            *reinterpret_cast<float4*>(&As[r][kq]) = av;
            const int kr = t >> 4, nc = (t & 15) * 4;
            float4 bv = *reinterpret_cast<const float4*>(&W[(size_t)(k0 + kr) * Dc + n0 + nc]);
            *reinterpret_cast<float4*>(&Bs[kr][nc]) = bv;
        }
        __syncthreads();
        #pragma unroll
        for (int kk = 0; kk < 16; ++kk) {
            float a[4], b[4];
            #pragma unroll
            for (int mi = 0; mi < 4; ++mi) a[mi] = As[ty * 4 + mi][kk];
            #pragma unroll
            for (int ni = 0; ni < 4; ++ni) b[ni] = Bs[kk][tx * 4 + ni];
            #pragma unroll
            for (int mi = 0; mi < 4; ++mi)
                #pragma unroll
                for (int ni = 0; ni < 4; ++ni)
                    acc[mi][ni] += a[mi] * b[ni];
        }
        __syncthreads();
    }
    #pragma unroll
    for (int mq = 0; mq < 4; ++mq) {
        const int gm = m0 + ty * 4 + mq;
        const int b = gm >> 11, s = gm & 2047;
        #pragma unroll
        for (int ni = 0; ni < 4; ++ni) {
            const int n  = n0 + tx * 4 + ni;
            const int h  = n & 15, dk = n >> 4;     // column = dk*16 + h
            Hd[((size_t)(b * Hc + h) * Sc + s) * DKc + dk] = acc[mq][ni];
        }
    }
}

// ---------------------------------------------------------------------------
// Kernel 2: flash-style f32 attention, restructured.
// 256 thr, TQ=64 queries/block, key tiles TK=64, 2 rows x 8 cols per thread.
// Wave-parallel softmax: row state (m,l) in registers, shfl_xor row reduce
// within each 8-lane row-group. Grid (S/64, B*H).
// ---------------------------------------------------------------------------
__global__ __launch_bounds__(256) void attn(const float* __restrict__ Qh,
                                            const float* __restrict__ Kh,
                                            const float* __restrict__ Vh,
                                            const int*   __restrict__ mask,
                                            float* __restrict__ att) {
    constexpr int TQ = 64, TK = 64;
    const int bh = blockIdx.y;                 // b*H + h
    const int b = bh >> 4, h = bh & 15;
    const int q0 = blockIdx.x * TQ;
    const float* Qb = Qh + ((size_t)bh * Sc + q0) * DKc;
    const float* Kb = Kh + (size_t)bh * Sc * DKc;
    const float* Vb = Vh + (size_t)bh * Sc * DKc;
    const int*   mb = mask + b * Sc;

    __shared__ float Qs[TQ][DKc + 4];          // 17.4 KB, stride 68
    __shared__ float Ks[TK][DKc + 4];          // 17.4 KB
    __shared__ float Vs[TK][DKc + 4];          // 17.4 KB
    __shared__ float Ps[TQ][TK + 1];           // 16.6 KB, stride 65
    __shared__ int   mk[TK];

    const int t  = threadIdx.x;
    const int rg = t >> 3;                     // row group 0..31
    const int ju = t & 7;                      // col sub-index
    const int r0 = rg * 2, r1 = r0 + 1;
    const int dch = ju * 8;                    // 8 dims of PV accumulator

    // stage Q once for the whole kernel
    for (int idx = t; idx < TQ * 16; idx += 256) {
        const int r = idx >> 4, dq = (idx & 15) * 4;
        *reinterpret_cast<float4*>(&Qs[r][dq]) =
            *reinterpret_cast<const float4*>(&Qb[(size_t)r * DKc + dq]);
    }

    float m0 = -1e30f, m1 = -1e30f, l0 = 0.0f, l1 = 0.0f;
    float acc0[8] = {}, acc1[8] = {};

    for (int k0 = 0; k0 < Sc; k0 += TK) {
        __syncthreads();                       // Qs ready (1st iter) / Ps,Vs free
        #pragma unroll
        for (int l = 0; l < 4; ++l) {
            const int idx = t + l * 256;       // float4 index 0..1023
            const int r = idx >> 4, dq = (idx & 15) * 4;
            *reinterpret_cast<float4*>(&Ks[r][dq]) =
                *reinterpret_cast<const float4*>(&Kb[(size_t)(k0 + r) * DKc + dq]);
            *reinterpret_cast<float4*>(&Vs[r][dq]) =
                *reinterpret_cast<const float4*>(&Vb[(size_t)(k0 + r) * DKc + dq]);
        }
        if (t < TK) mk[t] = mb[k0 + t];
        __syncthreads();

        // ---- scores: 2 rows x 8 cols per thread -------------------------
        float sc0[8] = {}, sc1[8] = {};
        #pragma unroll
        for (int d = 0; d < DKc; d += 4) {
            float4 qa = *reinterpret_cast<const float4*>(&Qs[r0][d]);
            float4 qb = *reinterpret_cast<const float4*>(&Qs[r1][d]);
            #pragma unroll
            for (int c = 0; c < 8; ++c) {
                float4 kv = *reinterpret_cast<const float4*>(&Ks[ju + 8 * c][d]);
                sc0[c] += qa.x * kv.x + qa.y * kv.y + qa.z * kv.z + qa.w * kv.w;
                sc1[c] += qb.x * kv.x + qb.y * kv.y + qb.z * kv.z + qb.w * kv.w;
            }
        }

        // ---- scale + key-mask + row max (parallel, in registers) --------
        float mx0 = -1e30f, mx1 = -1e30f;
        #pragma unroll
        for (int c = 0; c < 8; ++c) {
            const float mz = mk[ju + 8 * c] ? 0.0f : INFTY;
            sc0[c] = sc0[c] * 0.125f - mz;
            sc1[c] = sc1[c] * 0.125f - mz;
            mx0 = fmaxf(mx0, sc0[c]);
            mx1 = fmaxf(mx1, sc1[c]);
        }
        #pragma unroll
        for (int o = 1; o < 8; o <<= 1) {
            mx0 = fmaxf(mx0, __shfl_xor(mx0, o));
            mx1 = fmaxf(mx1, __shfl_xor(mx1, o));
        }
        const float mn0 = fmaxf(m0, mx0), mn1 = fmaxf(m1, mx1);
        const float rs0 = __expf(m0 - mn0), rs1 = __expf(m1 - mn1);
        float sum0 = 0.0f, sum1 = 0.0f;
        #pragma unroll
        for (int c = 0; c < 8; ++c) {
            const float p0 = __expf(sc0[c] - mn0);
            const float p1 = __expf(sc1[c] - mn1);
            sc0[c] = p0; sc1[c] = p1;
            sum0 += p0; sum1 += p1;
        }
        #pragma unroll
        for (int o = 1; o < 8; o <<= 1) {
            sum0 += __shfl_xor(sum0, o);
            sum1 += __shfl_xor(sum1, o);
        }
        m0 = mn0; m1 = mn1;
        l0 = l0 * rs0 + sum0;
        l1 = l1 * rs1 + sum1;

        // publish P tile
        #pragma unroll
        for (int c = 0; c < 8; ++c) {
            Ps[r0][ju + 8 * c] = sc0[c];
            Ps[r1][ju + 8 * c] = sc1[c];
        }
        __syncthreads();

        // ---- PV: rescale + accumulate -----------------------------------
        #pragma unroll
        for (int c = 0; c < 8; ++c) { acc0[c] *= rs0; acc1[c] *= rs1; }
        for (int j = 0; j < TK; ++j) {
            const float p0 = Ps[r0][j];
            const float p1 = Ps[r1][j];
            float4 va = *reinterpret_cast<const float4*>(&Vs[j][dch]);
            float4 vb = *reinterpret_cast<const float4*>(&Vs[j][dch + 4]);
            acc0[0] += p0 * va.x; acc0[1] += p0 * va.y; acc0[2] += p0 * va.z; acc0[3] += p0 * va.w;
            acc0[4] += p0 * vb.x; acc0[5] += p0 * vb.y; acc0[6] += p0 * vb.z; acc0[7] += p0 * vb.w;
            acc1[0] += p1 * va.x; acc1[1] += p1 * va.y; acc1[2] += p1 * va.z; acc1[3] += p1 * va.w;
            acc1[4] += p1 * vb.x; acc1[5] += p1 * vb.y; acc1[6] += p1 * vb.z; acc1[7] += p1 * vb.w;
        }
    }

    const float inv0 = 1.0f / l0, inv1 = 1.0f / l1;
    float* d0 = att + (size_t)(b * Sc + q0 + r0) * Dc + h * DKc + dch;
    float* d1 = att + (size_t)(b * Sc + q0 + r1) * Dc + h * DKc + dch;
    float4 o00 = make_float4(acc0[0] * inv0, acc0[1] * inv0, acc0[2] * inv0, acc0[3] * inv0);
    float4 o01 = make_float4(acc0[4] * inv0, acc0[5] * inv0, acc0[6] * inv0, acc0[7] * inv0);
    float4 o10 = make_float4(acc1[0] * inv1, acc1[1] * inv1, acc1[2] * inv1, acc1[3] * inv1);
    float4 o11 = make_float4(acc1[4] * inv1, acc1[5] * inv1, acc1[6] * inv1, acc1[7] * inv1);
    *reinterpret_cast<float4*>(d0)     = o00;
    *reinterpret_cast<float4*>(d0 + 4) = o01;
    *reinterpret_cast<float4*>(d1)     = o10;
    *reinterpret_cast<float4*>(d1 + 4) = o11;
}

// ---------------------------------------------------------------------------
// Kernel 3: output GEMM + query-mask + abs + f32 store.
// ---------------------------------------------------------------------------
__global__ __launch_bounds__(256) void gemm_oproj(const float* __restrict__ A,
                                                  const float* __restrict__ W,
                                                  const int*   __restrict__ mask,
                                                  float* __restrict__ out) {
    __shared__ float As[64][20];
    __shared__ float Bs[16][68];
    const int t  = threadIdx.x;
    const int tx = t & 15, ty = t >> 4;
    const int m0 = blockIdx.y * 64, n0 = blockIdx.x * 64;
    float acc[4][4] = {};
    for (int k0 = 0; k0 < Dc; k0 += 16) {
        {
            const int r = t >> 2, kq = (t & 3) * 4;
            float4 av = *reinterpret_cast<const float4*>(&A[(size_t)(m0 + r) * Dc + k0 + kq]);
            *reinterpret_cast<float4*>(&As[r][kq]) = av;
            const int kr = t >> 4, nc = (t & 15) * 4;
            float4 bv = *reinterpret_cast<const float4*>(&W[(size_t)(k0 + kr) * Dc + n0 + nc]);
            *reinterpret_cast<float4*>(&Bs[kr][nc]) = bv;
        }
        __syncthreads();
        #pragma unroll
        for (int kk = 0; kk < 16; ++kk) {
            float a[4], b[4];
            #pragma unroll
            for (int mi = 0; mi < 4; ++mi) a[mi] = As[ty * 4 + mi][kk];
            #pragma unroll
            for (int ni = 0; ni < 4; ++ni) b[ni] = Bs[kk][tx * 4 + ni];
            #pragma unroll
            for (int mi = 0; mi < 4; ++mi)
                #pragma unroll
                for (int ni = 0; ni < 4; ++ni)
                    acc[mi][ni] += a[mi] * b[ni];
        }
        __syncthreads();
    }
    #pragma unroll
    for (int mq = 0; mq < 4; ++mq) {
        const int gm = m0 + ty * 4 + mq;
        const int mv = mask[gm];
        #pragma unroll
        for (int ni = 0; ni < 4; ++ni) {
            const float o = mv ? fabsf(acc[mq][ni]) : 0.0f;
            out[(size_t)gm * Dc + n0 + tx * 4 + ni] = o;
        }
    }
}

// ---------------------------------------------------------------------------
extern "C" void kernel_launch(void* const* d_in, const int* in_sizes, int n_in,
                              void* d_out, int out_size, void* d_ws, size_t ws_size,
                              hipStream_t stream) {
    const float* x    = (const float*)d_in[0];
    const void*  mraw = d_in[1];
    const float* WQ   = (const float*)d_in[2];
    const float* WK   = (const float*)d_in[3];
    const float* WV   = (const float*)d_in[4];
    const float* WO   = (const float*)d_in[5];
    float* out = (float*)d_out;

    // ws layout: mask_i (32 KB) | Qh | Kh | Vh | att   (4 x 33.55 MB f32)
    int*   mi   = (int*)d_ws;
    float* base = (float*)((char*)d_ws + 32768);
    const size_t SZ = (size_t)Mtot * Dc;
    float* Qh  = base;
    float* Kh  = base + SZ;
    float* Vh  = base + 2 * SZ;
    float* att = base + 3 * SZ;

    mask_norm<<<1, 256, 0, stream>>>(mraw, mi);

    const dim3 gGemm(Dc / 64, Mtot / 64);      // (16,128)
    gemm_proj<<<gGemm, 256, 0, stream>>>(x, WQ, Qh);
    gemm_proj<<<gGemm, 256, 0, stream>>>(x, WK, Kh);
    gemm_proj<<<gGemm, 256, 0, stream>>>(x, WV, Vh);

    attn<<<dim3(Sc / 64, Bc * Hc), 256, 0, stream>>>(Qh, Kh, Vh, mi, att);

    gemm_oproj<<<gGemm, 256, 0, stream>>>(att, WO, mi, out);
}

// Round 5
// 1266.371 us; speedup vs baseline: 2.2171x; 1.7647x over previous
//
#include <hip/hip_runtime.h>
#include <hip/hip_bf16.h>
#include <cstdint>
#include <cstddef>

constexpr int Bc  = 4;
constexpr int Sc  = 2048;
constexpr int Dc  = 1024;
constexpr int Hc  = 16;
constexpr int DKc = 64;
constexpr int Mtot = Bc * Sc;              // 8192 rows
constexpr float INFTY = 1000000.0f;

typedef short bf16x8 __attribute__((ext_vector_type(8)));
typedef float f32x4  __attribute__((ext_vector_type(4)));

__device__ inline unsigned short bf16_rn(float f) {
    uint32_t u = __float_as_uint(f);
    uint32_t r = (u + 0x7FFFu + ((u >> 16) & 1u)) >> 16;
    return (unsigned short)r;
}

// ---------------------------------------------------------------------------
// Kernel 0: normalize padding mask to int32[8192] regardless of shipped dtype.
// ---------------------------------------------------------------------------
__global__ __launch_bounds__(256) void mask_norm(const void* __restrict__ mraw,
                                                 int* __restrict__ mi) {
    __shared__ int fF32, fU8, fI32;
    if (threadIdx.x == 0) { fF32 = 0; fU8 = 0; fI32 = 0; }
    __syncthreads();
    const unsigned char* mb = (const unsigned char*)mraw;
    int aF = 0, a1 = 0, a4 = 0;
    for (int i = threadIdx.x; i < Mtot; i += 256) {
        unsigned char v = mb[i];
        if ((i & 3) == 3 && v == 0x3F) aF = 1;
        if (v) {
            if (i & 3) a1 = 1;
            else if (i & 7) a4 = 1;
        }
    }
    if (aF) fF32 = 1;
    if (a1) fU8 = 1;
    if (a4) fI32 = 1;
    __syncthreads();
    if (fF32) {
        const float* mf = (const float*)mraw;
        for (int s = threadIdx.x; s < Mtot; s += 256) mi[s] = (mf[s] != 0.0f);
    } else if (fU8) {
        for (int s = threadIdx.x; s < Mtot; s += 256) mi[s] = (mb[s] != 0);
    } else if (fI32) {
        const int* m32 = (const int*)mraw;
        for (int s = threadIdx.x; s < Mtot; s += 256) mi[s] = (m32[s] != 0);
    } else {
        const long long* m64 = (const long long*)mraw;
        for (int s = threadIdx.x; s < Mtot; s += 256) mi[s] = (m64[s] != 0);
    }
}

// ---------------------------------------------------------------------------
// Kernel 1a: f32 GEMM P = A@W, epilogue -> split bf16 (hi,lo), head layout
// [bh][s][dk] where head h = column (dk*16 + h).
// ---------------------------------------------------------------------------
__global__ __launch_bounds__(256) void gemm_proj_qk(const float* __restrict__ A,
                                                    const float* __restrict__ W,
                                                    unsigned short* __restrict__ Phi,
                                                    unsigned short* __restrict__ Plo) {
    __shared__ float As[64][20];
    __shared__ float Bs[16][68];
    const int t  = threadIdx.x;
    const int tx = t & 15, ty = t >> 4;
    const int m0 = blockIdx.y * 64, n0 = blockIdx.x * 64;
    float acc[4][4] = {};
    for (int k0 = 0; k0 < Dc; k0 += 16) {
        {
            const int r = t >> 2, kq = (t & 3) * 4;
            float4 av = *reinterpret_cast<const float4*>(&A[(size_t)(m0 + r) * Dc + k0 + kq]);
            *reinterpret_cast<float4*>(&As[r][kq]) = av;
            const int kr = t >> 4, nc = (t & 15) * 4;
            float4 bv = *reinterpret_cast<const float4*>(&W[(size_t)(k0 + kr) * Dc + n0 + nc]);
            *reinterpret_cast<float4*>(&Bs[kr][nc]) = bv;
        }
        __syncthreads();
        #pragma unroll
        for (int kk = 0; kk < 16; ++kk) {
            float a[4], b[4];
            #pragma unroll
            for (int mi = 0; mi < 4; ++mi) a[mi] = As[ty * 4 + mi][kk];
            #pragma unroll
            for (int ni = 0; ni < 4; ++ni) b[ni] = Bs[kk][tx * 4 + ni];
            #pragma unroll
            for (int mi = 0; mi < 4; ++mi)
                #pragma unroll
                for (int ni = 0; ni < 4; ++ni)
                    acc[mi][ni] += a[mi] * b[ni];
        }
        __syncthreads();
    }
    #pragma unroll
    for (int mq = 0; mq < 4; ++mq) {
        const int gm = m0 + ty * 4 + mq;
        const int b = gm >> 11, s = gm & 2047;
        #pragma unroll
        for (int ni = 0; ni < 4; ++ni) {
            const int n  = n0 + tx * 4 + ni;
            const int h  = n & 15, dk = n >> 4;
            const size_t o = ((size_t)(b * Hc + h) * Sc + s) * DKc + dk;
            const float v = acc[mq][ni];
            const unsigned short hi = bf16_rn(v);
            const float hif = __uint_as_float((uint32_t)hi << 16);
            Phi[o] = hi;
            Plo[o] = bf16_rn(v - hif);
        }
    }
}

// ---------------------------------------------------------------------------
// Kernel 1b: f32 GEMM, epilogue -> bf16 V TRANSPOSED: Vt[bh][dk][s].
// ---------------------------------------------------------------------------
__global__ __launch_bounds__(256) void gemm_proj_vt(const float* __restrict__ A,
                                                    const float* __restrict__ W,
                                                    unsigned short* __restrict__ Vt) {
    __shared__ float As[64][20];
    __shared__ float Bs[16][68];
    const int t  = threadIdx.x;
    const int tx = t & 15, ty = t >> 4;
    const int m0 = blockIdx.y * 64, n0 = blockIdx.x * 64;
    float acc[4][4] = {};
    for (int k0 = 0; k0 < Dc; k0 += 16) {
        {
            const int r = t >> 2, kq = (t & 3) * 4;
            float4 av = *reinterpret_cast<const float4*>(&A[(size_t)(m0 + r) * Dc + k0 + kq]);
            *reinterpret_cast<float4*>(&As[r][kq]) = av;
            const int kr = t >> 4, nc = (t & 15) * 4;
            float4 bv = *reinterpret_cast<const float4*>(&W[(size_t)(k0 + kr) * Dc + n0 + nc]);
            *reinterpret_cast<float4*>(&Bs[kr][nc]) = bv;
        }
        __syncthreads();
        #pragma unroll
        for (int kk = 0; kk < 16; ++kk) {
            float a[4], b[4];
            #pragma unroll
            for (int mi = 0; mi < 4; ++mi) a[mi] = As[ty * 4 + mi][kk];
            #pragma unroll
            for (int ni = 0; ni < 4; ++ni) b[ni] = Bs[kk][tx * 4 + ni];
            #pragma unroll
            for (int mi = 0; mi < 4; ++mi)
                #pragma unroll
                for (int ni = 0; ni < 4; ++ni)
                    acc[mi][ni] += a[mi] * b[ni];
        }
        __syncthreads();
    }
    #pragma unroll
    for (int mq = 0; mq < 4; ++mq) {
        const int gm = m0 + ty * 4 + mq;
        const int b = gm >> 11, s = gm & 2047;
        #pragma unroll
        for (int ni = 0; ni < 4; ++ni) {
            const int n  = n0 + tx * 4 + ni;
            const int h  = n & 15, dk = n >> 4;
            Vt[((size_t)(b * Hc + h) * DKc + dk) * Sc + s] = bf16_rn(acc[mq][ni]);
        }
    }
}

// ---------------------------------------------------------------------------
// Kernel 2: MFMA flash attention. 256 thr = 4 waves, TQ=64 (16 rows/wave),
// TK=64 per tile. QK^T = split-bf16 3-term MFMA (f32-equivalent logits);
// PV = bf16 MFMA. Online softmax in registers on the C-layout
// (col=lane&15, row=(lane>>4)*4+reg). Grid (S/64, B*H).
// ---------------------------------------------------------------------------
__global__ __launch_bounds__(256) void attn_mfma(const unsigned short* __restrict__ Qhi,
                                                 const unsigned short* __restrict__ Qlo,
                                                 const unsigned short* __restrict__ Khi,
                                                 const unsigned short* __restrict__ Klo,
                                                 const unsigned short* __restrict__ Vtg,
                                                 const int*   __restrict__ mask,
                                                 float* __restrict__ att) {
    constexpr int TK = 64;
    const int bh = blockIdx.y;
    const int b = bh >> 4, h = bh & 15;
    const int q0 = blockIdx.x * 64;
    const int*   mb = mask + b * Sc;

    __shared__ __align__(16) unsigned short KsH[64][72];
    __shared__ __align__(16) unsigned short KsL[64][72];
    __shared__ __align__(16) unsigned short Vs[64][72];   // Vs[d][key]
    __shared__ __align__(16) unsigned short Ps[64][72];
    __shared__ int mk[TK];

    const int t    = threadIdx.x;
    const int wave = t >> 6;
    const int lane = t & 63;
    const int lg   = lane >> 4;        // k-octet group 0..3
    const int li   = lane & 15;        // row/col within fragment

    // Q A-fragments held in registers for the whole kernel.
    // A[m=q][k=d]: lane holds rows q = wave*16 + li, d = c*32 + lg*8 + [0..7]
    const size_t qrow = ((size_t)bh * Sc + q0 + wave * 16 + li) * DKc + lg * 8;
    const bf16x8 qh0 = *reinterpret_cast<const bf16x8*>(Qhi + qrow);
    const bf16x8 qh1 = *reinterpret_cast<const bf16x8*>(Qhi + qrow + 32);
    const bf16x8 ql0 = *reinterpret_cast<const bf16x8*>(Qlo + qrow);
    const bf16x8 ql1 = *reinterpret_cast<const bf16x8*>(Qlo + qrow + 32);

    const size_t kbase = (size_t)bh * Sc * DKc;            // Khi/Klo [bh][s][dk]
    const size_t vbase = (size_t)bh * DKc * Sc;            // Vt [bh][dk][s]

    f32x4 accO[4] = {f32x4{0,0,0,0}, f32x4{0,0,0,0}, f32x4{0,0,0,0}, f32x4{0,0,0,0}};
    float m[4] = {-1e30f, -1e30f, -1e30f, -1e30f};
    float l[4] = {0.0f, 0.0f, 0.0f, 0.0f};

    for (int k0 = 0; k0 < Sc; k0 += TK) {
        __syncthreads();                       // prev tile's Ks/Vs reads done
        #pragma unroll
        for (int u = 0; u < 2; ++u) {
            const int idx = t + u * 256;       // 0..511 -> 64 rows x 8 chunks(16B)
            const int r = idx >> 3, cc = (idx & 7) * 8;
            *reinterpret_cast<uint4*>(&KsH[r][cc]) =
                *reinterpret_cast<const uint4*>(Khi + kbase + (size_t)(k0 + r) * DKc + cc);
            *reinterpret_cast<uint4*>(&KsL[r][cc]) =
                *reinterpret_cast<const uint4*>(Klo + kbase + (size_t)(k0 + r) * DKc + cc);
            *reinterpret_cast<uint4*>(&Vs[r][cc]) =
                *reinterpret_cast<const uint4*>(Vtg + vbase + (size_t)r * Sc + k0 + cc);
        }
        if (t < TK) mk[t] = mb[k0 + t];
        __syncthreads();

        // ---- QK^T: 4 col-tiles x (2 k-chunks x 3 split terms) ----------
        float sc[4][4];
        #pragma unroll
        for (int n = 0; n < 4; ++n) {
            // B[k=d][j=key]: lane holds key = n*16 + li, d = c*32 + lg*8 + [0..7]
            const bf16x8 bh0 = *reinterpret_cast<const bf16x8*>(&KsH[n * 16 + li][lg * 8]);
            const bf16x8 bh1 = *reinterpret_cast<const bf16x8*>(&KsH[n * 16 + li][32 + lg * 8]);
            const bf16x8 bl0 = *reinterpret_cast<const bf16x8*>(&KsL[n * 16 + li][lg * 8]);
            const bf16x8 bl1 = *reinterpret_cast<const bf16x8*>(&KsL[n * 16 + li][32 + lg * 8]);
            f32x4 a = {0, 0, 0, 0};
            a = __builtin_amdgcn_mfma_f32_16x16x32_bf16(qh0, bh0, a, 0, 0, 0);
            a = __builtin_amdgcn_mfma_f32_16x16x32_bf16(qh1, bh1, a, 0, 0, 0);
            a = __builtin_amdgcn_mfma_f32_16x16x32_bf16(qh0, bl0, a, 0, 0, 0);
            a = __builtin_amdgcn_mfma_f32_16x16x32_bf16(qh1, bl1, a, 0, 0, 0);
            a = __builtin_amdgcn_mfma_f32_16x16x32_bf16(ql0, bh0, a, 0, 0, 0);
            a = __builtin_amdgcn_mfma_f32_16x16x32_bf16(ql1, bh1, a, 0, 0, 0);
            const float mz = mk[n * 16 + li] ? 0.0f : INFTY;
            #pragma unroll
            for (int r = 0; r < 4; ++r) sc[n][r] = a[r] * 0.125f - mz;
        }

        // ---- online softmax (rows = lg*4 + r, reduce over 16 li-lanes) --
        float mx[4], rs[4], sum[4];
        #pragma unroll
        for (int r = 0; r < 4; ++r)
            mx[r] = fmaxf(fmaxf(sc[0][r], sc[1][r]), fmaxf(sc[2][r], sc[3][r]));
        #pragma unroll
        for (int o = 1; o < 16; o <<= 1)
            #pragma unroll
            for (int r = 0; r < 4; ++r) mx[r] = fmaxf(mx[r], __shfl_xor(mx[r], o));
        #pragma unroll
        for (int r = 0; r < 4; ++r) {
            const float mn = fmaxf(m[r], mx[r]);
            rs[r] = __expf(m[r] - mn);
            m[r]  = mn;
            sum[r] = 0.0f;
        }
        #pragma unroll
        for (int n = 0; n < 4; ++n)
            #pragma unroll
            for (int r = 0; r < 4; ++r) {
                const float p = __expf(sc[n][r] - m[r]);
                sc[n][r] = p;
                sum[r] += p;
            }
        #pragma unroll
        for (int o = 1; o < 16; o <<= 1)
            #pragma unroll
            for (int r = 0; r < 4; ++r) sum[r] += __shfl_xor(sum[r], o);
        #pragma unroll
        for (int r = 0; r < 4; ++r) l[r] = l[r] * rs[r] + sum[r];

        // publish P strip (rows wave*16 + lg*4 + r, col li + 16n) as bf16
        #pragma unroll
        for (int n = 0; n < 4; ++n)
            #pragma unroll
            for (int r = 0; r < 4; ++r)
                Ps[wave * 16 + lg * 4 + r][li + 16 * n] = bf16_rn(sc[n][r]);

        // rescale O accumulator
        #pragma unroll
        for (int dt = 0; dt < 4; ++dt)
            #pragma unroll
            for (int r = 0; r < 4; ++r) accO[dt][r] *= rs[r];

        // ---- PV: A = P strip (wave-local, no barrier needed), B = V^T ---
        #pragma unroll
        for (int c = 0; c < 2; ++c) {
            const bf16x8 pa = *reinterpret_cast<const bf16x8*>(&Ps[wave * 16 + li][c * 32 + lg * 8]);
            #pragma unroll
            for (int dt = 0; dt < 4; ++dt) {
                const bf16x8 vb = *reinterpret_cast<const bf16x8*>(&Vs[dt * 16 + li][c * 32 + lg * 8]);
                accO[dt] = __builtin_amdgcn_mfma_f32_16x16x32_bf16(pa, vb, accO[dt], 0, 0, 0);
            }
        }
    }

    float inv[4];
    #pragma unroll
    for (int r = 0; r < 4; ++r) inv[r] = 1.0f / l[r];
    #pragma unroll
    for (int dt = 0; dt < 4; ++dt)
        #pragma unroll
        for (int r = 0; r < 4; ++r) {
            const int q = q0 + wave * 16 + lg * 4 + r;
            att[((size_t)(b * Sc + q)) * Dc + h * DKc + li + 16 * dt] = accO[dt][r] * inv[r];
        }
}

// ---------------------------------------------------------------------------
// Kernel 3: output GEMM + query-mask + abs + f32 store.
// ---------------------------------------------------------------------------
__global__ __launch_bounds__(256) void gemm_oproj(const float* __restrict__ A,
                                                  const float* __restrict__ W,
                                                  const int*   __restrict__ mask,
                                                  float* __restrict__ out) {
    __shared__ float As[64][20];
    __shared__ float Bs[16][68];
    const int t  = threadIdx.x;
    const int tx = t & 15, ty = t >> 4;
    const int m0 = blockIdx.y * 64, n0 = blockIdx.x * 64;
    float acc[4][4] = {};
    for (int k0 = 0; k0 < Dc; k0 += 16) {
        {
            const int r = t >> 2, kq = (t & 3) * 4;
            float4 av = *reinterpret_cast<const float4*>(&A[(size_t)(m0 + r) * Dc + k0 + kq]);
            *reinterpret_cast<float4*>(&As[r][kq]) = av;
            const int kr = t >> 4, nc = (t & 15) * 4;
            float4 bv = *reinterpret_cast<const float4*>(&W[(size_t)(k0 + kr) * Dc + n0 + nc]);
            *reinterpret_cast<float4*>(&Bs[kr][nc]) = bv;
        }
        __syncthreads();
        #pragma unroll
        for (int kk = 0; kk < 16; ++kk) {
            float a[4], b[4];
            #pragma unroll
            for (int mi = 0; mi < 4; ++mi) a[mi] = As[ty * 4 + mi][kk];
            #pragma unroll
            for (int ni = 0; ni < 4; ++ni) b[ni] = Bs[kk][tx * 4 + ni];
            #pragma unroll
            for (int mi = 0; mi < 4; ++mi)
                #pragma unroll
                for (int ni = 0; ni < 4; ++ni)
                    acc[mi][ni] += a[mi] * b[ni];
        }
        __syncthreads();
    }
    #pragma unroll
    for (int mq = 0; mq < 4; ++mq) {
        const int gm = m0 + ty * 4 + mq;
        const int mv = mask[gm];
        #pragma unroll
        for (int ni = 0; ni < 4; ++ni) {
            const float o = mv ? fabsf(acc[mq][ni]) : 0.0f;
            out[(size_t)gm * Dc + n0 + tx * 4 + ni] = o;
        }
    }
}

// ---------------------------------------------------------------------------
extern "C" void kernel_launch(void* const* d_in, const int* in_sizes, int n_in,
                              void* d_out, int out_size, void* d_ws, size_t ws_size,
                              hipStream_t stream) {
    const float* x    = (const float*)d_in[0];
    const void*  mraw = d_in[1];
    const float* WQ   = (const float*)d_in[2];
    const float* WK   = (const float*)d_in[3];
    const float* WV   = (const float*)d_in[4];
    const float* WO   = (const float*)d_in[5];
    float* out = (float*)d_out;

    // ws: mask_i(32KB) | Qhi Qlo Khi Klo Vt (5 x 16.78MB bf16) | att (33.55MB f32)
    int* mi = (int*)d_ws;
    const size_t SZ = (size_t)Mtot * Dc;       // 8.39M elements
    unsigned short* b16 = (unsigned short*)((char*)d_ws + 32768);
    unsigned short* Qhi = b16;
    unsigned short* Qlo = b16 + SZ;
    unsigned short* Khi = b16 + 2 * SZ;
    unsigned short* Klo = b16 + 3 * SZ;
    unsigned short* Vt  = b16 + 4 * SZ;
    float* att = (float*)((char*)d_ws + 32768 + 5 * SZ * sizeof(unsigned short));

    mask_norm<<<1, 256, 0, stream>>>(mraw, mi);

    const dim3 gGemm(Dc / 64, Mtot / 64);      // (16,128)
    gemm_proj_qk<<<gGemm, 256, 0, stream>>>(x, WQ, Qhi, Qlo);
    gemm_proj_qk<<<gGemm, 256, 0, stream>>>(x, WK, Khi, Klo);
    gemm_proj_vt<<<gGemm, 256, 0, stream>>>(x, WV, Vt);

    attn_mfma<<<dim3(Sc / 64, Bc * Hc), 256, 0, stream>>>(Qhi, Qlo, Khi, Klo, Vt, mi, att);

    gemm_oproj<<<gGemm, 256, 0, stream>>>(att, WO, mi, out);
}

// Round 6
// 562.529 us; speedup vs baseline: 4.9912x; 2.2512x over previous
//
#include <hip/hip_runtime.h>
#include <hip/hip_bf16.h>
#include <cstdint>
#include <cstddef>

constexpr int Bc  = 4;
constexpr int Sc  = 2048;
constexpr int Dc  = 1024;
constexpr int Hc  = 16;
constexpr int DKc = 64;
constexpr int Mtot = Bc * Sc;              // 8192 rows
constexpr float INFTY = 1000000.0f;

typedef short bf16x8 __attribute__((ext_vector_type(8)));
typedef float f32x4  __attribute__((ext_vector_type(4)));

__device__ inline unsigned short bf16_rn(float f) {
    uint32_t u = __float_as_uint(f);
    uint32_t r = (u + 0x7FFFu + ((u >> 16) & 1u)) >> 16;
    return (unsigned short)r;
}

// ---------------------------------------------------------------------------
// Kernel 0: normalize padding mask to int32[8192] regardless of shipped dtype.
// ---------------------------------------------------------------------------
__global__ __launch_bounds__(256) void mask_norm(const void* __restrict__ mraw,
                                                 int* __restrict__ mi) {
    __shared__ int fF32, fU8, fI32;
    if (threadIdx.x == 0) { fF32 = 0; fU8 = 0; fI32 = 0; }
    __syncthreads();
    const unsigned char* mb = (const unsigned char*)mraw;
    int aF = 0, a1 = 0, a4 = 0;
    for (int i = threadIdx.x; i < Mtot; i += 256) {
        unsigned char v = mb[i];
        if ((i & 3) == 3 && v == 0x3F) aF = 1;
        if (v) {
            if (i & 3) a1 = 1;
            else if (i & 7) a4 = 1;
        }
    }
    if (aF) fF32 = 1;
    if (a1) fU8 = 1;
    if (a4) fI32 = 1;
    __syncthreads();
    if (fF32) {
        const float* mf = (const float*)mraw;
        for (int s = threadIdx.x; s < Mtot; s += 256) mi[s] = (mf[s] != 0.0f);
    } else if (fU8) {
        for (int s = threadIdx.x; s < Mtot; s += 256) mi[s] = (mb[s] != 0);
    } else if (fI32) {
        const int* m32 = (const int*)mraw;
        for (int s = threadIdx.x; s < Mtot; s += 256) mi[s] = (m32[s] != 0);
    } else {
        const long long* m64 = (const long long*)mraw;
        for (int s = threadIdx.x; s < Mtot; s += 256) mi[s] = (m64[s] != 0);
    }
}

// ---------------------------------------------------------------------------
// Kernel P1: split x (f32) -> xhi + xlo (bf16), row-major [M][D].
// ---------------------------------------------------------------------------
__global__ __launch_bounds__(256) void split_x(const float* __restrict__ x,
                                               unsigned short* __restrict__ xhi,
                                               unsigned short* __restrict__ xlo) {
    const int i = (blockIdx.x * 256 + threadIdx.x) * 4;
    float4 v = *reinterpret_cast<const float4*>(x + i);
    ushort4 h, l;
    h.x = bf16_rn(v.x); l.x = bf16_rn(v.x - __uint_as_float((uint32_t)h.x << 16));
    h.y = bf16_rn(v.y); l.y = bf16_rn(v.y - __uint_as_float((uint32_t)h.y << 16));
    h.z = bf16_rn(v.z); l.z = bf16_rn(v.z - __uint_as_float((uint32_t)h.z << 16));
    h.w = bf16_rn(v.w); l.w = bf16_rn(v.w - __uint_as_float((uint32_t)h.w << 16));
    *reinterpret_cast<ushort4*>(xhi + i) = h;
    *reinterpret_cast<ushort4*>(xlo + i) = l;
}

// ---------------------------------------------------------------------------
// Kernel P2: split + transpose W (f32 [K][N]) -> WhT (+WlT) bf16 [N][K].
// ---------------------------------------------------------------------------
template<bool WLO>
__global__ __launch_bounds__(256) void split_wt(const float* __restrict__ W,
                                                unsigned short* __restrict__ WhT,
                                                unsigned short* __restrict__ WlT) {
    __shared__ float ls[64][68];
    const int k0 = blockIdx.y * 64, n0 = blockIdx.x * 64;
    const int t = threadIdx.x;
    #pragma unroll
    for (int l = 0; l < 4; ++l) {
        const int idx = t + l * 256;
        const int r = idx >> 4, c = (idx & 15) * 4;
        *reinterpret_cast<float4*>(&ls[r][c]) =
            *reinterpret_cast<const float4*>(W + (size_t)(k0 + r) * Dc + n0 + c);
    }
    __syncthreads();
    #pragma unroll
    for (int l = 0; l < 4; ++l) {
        const int idx = t + l * 256;
        const int on = idx >> 4, kq = (idx & 15) * 4;
        float v0 = ls[kq + 0][on], v1 = ls[kq + 1][on], v2 = ls[kq + 2][on], v3 = ls[kq + 3][on];
        ushort4 h;
        h.x = bf16_rn(v0); h.y = bf16_rn(v1); h.z = bf16_rn(v2); h.w = bf16_rn(v3);
        *reinterpret_cast<ushort4*>(WhT + (size_t)(n0 + on) * Dc + k0 + kq) = h;
        if (WLO) {
            ushort4 lo;
            lo.x = bf16_rn(v0 - __uint_as_float((uint32_t)h.x << 16));
            lo.y = bf16_rn(v1 - __uint_as_float((uint32_t)h.y << 16));
            lo.z = bf16_rn(v2 - __uint_as_float((uint32_t)h.z << 16));
            lo.w = bf16_rn(v3 - __uint_as_float((uint32_t)h.w << 16));
            *reinterpret_cast<ushort4*>(WlT + (size_t)(n0 + on) * Dc + k0 + kq) = lo;
        }
    }
}

// ---------------------------------------------------------------------------
// Kernel G: split-bf16 MFMA GEMM, 128x128 tile, 4 waves (2x2 of 64x64),
// BK=32. A=[M][K] (hi,lo), B=W^T=[N][K] (hi,lo).
// NTERMS=1: AH*BH.  NTERMS=3: AH*BH + AH*BL + AL*BH (f32-equivalent).
// EPI: 0 = split-head hi/lo ([bh][s][dk]); 1 = V^T bf16 ([bh][dk][s]);
//      2 = mask+abs+f32 out.
// ---------------------------------------------------------------------------
template<int NTERMS, int EPI>
__global__ __launch_bounds__(256) void gemm_mfma(
    const unsigned short* __restrict__ Ahi, const unsigned short* __restrict__ Alo,
    const unsigned short* __restrict__ Bhi, const unsigned short* __restrict__ Blo,
    const int* __restrict__ mask,
    unsigned short* __restrict__ O1, unsigned short* __restrict__ O2,
    float* __restrict__ Of) {
    __shared__ __align__(16) unsigned short Ah[128][40];
    __shared__ __align__(16) unsigned short Al[128][40];
    __shared__ __align__(16) unsigned short Bh[128][40];
    __shared__ __align__(16) unsigned short Bl[128][40];
    const int t = threadIdx.x;
    const int n0 = blockIdx.x * 128, m0 = blockIdx.y * 128;
    const int wave = t >> 6, lane = t & 63, li = lane & 15, lg = lane >> 4;
    const int wm = (wave >> 1) * 64, wn = (wave & 1) * 64;
    const int srow = t >> 1, sh = (t & 1) * 16;

    f32x4 acc[4][4] = {};

    for (int k0 = 0; k0 < Dc; k0 += 32) {
        __syncthreads();
        {
            const size_t ga = (size_t)(m0 + srow) * Dc + k0 + sh;
            const size_t gb = (size_t)(n0 + srow) * Dc + k0 + sh;
            *reinterpret_cast<uint4*>(&Ah[srow][sh])     = *reinterpret_cast<const uint4*>(Ahi + ga);
            *reinterpret_cast<uint4*>(&Ah[srow][sh + 8]) = *reinterpret_cast<const uint4*>(Ahi + ga + 8);
            *reinterpret_cast<uint4*>(&Bh[srow][sh])     = *reinterpret_cast<const uint4*>(Bhi + gb);
            *reinterpret_cast<uint4*>(&Bh[srow][sh + 8]) = *reinterpret_cast<const uint4*>(Bhi + gb + 8);
            if (NTERMS == 3) {
                *reinterpret_cast<uint4*>(&Al[srow][sh])     = *reinterpret_cast<const uint4*>(Alo + ga);
                *reinterpret_cast<uint4*>(&Al[srow][sh + 8]) = *reinterpret_cast<const uint4*>(Alo + ga + 8);
                *reinterpret_cast<uint4*>(&Bl[srow][sh])     = *reinterpret_cast<const uint4*>(Blo + gb);
                *reinterpret_cast<uint4*>(&Bl[srow][sh + 8]) = *reinterpret_cast<const uint4*>(Blo + gb + 8);
            }
        }
        __syncthreads();

        bf16x8 bhf[4], blf[4];
        #pragma unroll
        for (int ni = 0; ni < 4; ++ni) {
            bhf[ni] = *reinterpret_cast<const bf16x8*>(&Bh[wn + ni * 16 + li][lg * 8]);
            if (NTERMS == 3)
                blf[ni] = *reinterpret_cast<const bf16x8*>(&Bl[wn + ni * 16 + li][lg * 8]);
        }
        #pragma unroll
        for (int mi = 0; mi < 4; ++mi) {
            const bf16x8 ahf = *reinterpret_cast<const bf16x8*>(&Ah[wm + mi * 16 + li][lg * 8]);
            bf16x8 alf = {};
            if (NTERMS == 3)
                alf = *reinterpret_cast<const bf16x8*>(&Al[wm + mi * 16 + li][lg * 8]);
            #pragma unroll
            for (int ni = 0; ni < 4; ++ni) {
                acc[mi][ni] = __builtin_amdgcn_mfma_f32_16x16x32_bf16(ahf, bhf[ni], acc[mi][ni], 0, 0, 0);
                if (NTERMS == 3) {
                    acc[mi][ni] = __builtin_amdgcn_mfma_f32_16x16x32_bf16(ahf, blf[ni], acc[mi][ni], 0, 0, 0);
                    acc[mi][ni] = __builtin_amdgcn_mfma_f32_16x16x32_bf16(alf, bhf[ni], acc[mi][ni], 0, 0, 0);
                }
            }
        }
    }

    // epilogue: C mapping col = li, row = lg*4 + r (m89-verified)
    #pragma unroll
    for (int mi = 0; mi < 4; ++mi) {
        #pragma unroll
        for (int r = 0; r < 4; ++r) {
            const int m = m0 + wm + mi * 16 + lg * 4 + r;
            #pragma unroll
            for (int ni = 0; ni < 4; ++ni) {
                const int n = n0 + wn + ni * 16 + li;
                const float v = acc[mi][ni][r];
                if (EPI == 0) {
                    const int b = m >> 11, s = m & 2047, h = n & 15, dk = n >> 4;
                    const size_t o = ((size_t)(b * Hc + h) * Sc + s) * DKc + dk;
                    const unsigned short hi = bf16_rn(v);
                    O1[o] = hi;
                    O2[o] = bf16_rn(v - __uint_as_float((uint32_t)hi << 16));
                } else if (EPI == 1) {
                    const int b = m >> 11, s = m & 2047, h = n & 15, dk = n >> 4;
                    O1[((size_t)(b * Hc + h) * DKc + dk) * Sc + s] = bf16_rn(v);
                } else {
                    Of[(size_t)m * Dc + n] = mask[m] ? fabsf(v) : 0.0f;
                }
            }
        }
    }
}

// ---------------------------------------------------------------------------
// Kernel 2: MFMA flash attention (unchanged math from round 5); epilogue now
// emits split hi/lo bf16 att for the 3-term O-projection.
// ---------------------------------------------------------------------------
__global__ __launch_bounds__(256) void attn_mfma(const unsigned short* __restrict__ Qhi,
                                                 const unsigned short* __restrict__ Qlo,
                                                 const unsigned short* __restrict__ Khi,
                                                 const unsigned short* __restrict__ Klo,
                                                 const unsigned short* __restrict__ Vtg,
                                                 const int*   __restrict__ mask,
                                                 unsigned short* __restrict__ atthi,
                                                 unsigned short* __restrict__ attlo) {
    constexpr int TK = 64;
    const int bh = blockIdx.y;
    const int b = bh >> 4, h = bh & 15;
    const int q0 = blockIdx.x * 64;
    const int* mb = mask + b * Sc;

    __shared__ __align__(16) unsigned short KsH[64][72];
    __shared__ __align__(16) unsigned short KsL[64][72];
    __shared__ __align__(16) unsigned short Vs[64][72];   // Vs[d][key]
    __shared__ __align__(16) unsigned short Ps[64][72];
    __shared__ int mk[TK];

    const int t    = threadIdx.x;
    const int wave = t >> 6;
    const int lane = t & 63;
    const int lg   = lane >> 4;
    const int li   = lane & 15;

    const size_t qrow = ((size_t)bh * Sc + q0 + wave * 16 + li) * DKc + lg * 8;
    const bf16x8 qh0 = *reinterpret_cast<const bf16x8*>(Qhi + qrow);
    const bf16x8 qh1 = *reinterpret_cast<const bf16x8*>(Qhi + qrow + 32);
    const bf16x8 ql0 = *reinterpret_cast<const bf16x8*>(Qlo + qrow);
    const bf16x8 ql1 = *reinterpret_cast<const bf16x8*>(Qlo + qrow + 32);

    const size_t kbase = (size_t)bh * Sc * DKc;
    const size_t vbase = (size_t)bh * DKc * Sc;

    f32x4 accO[4] = {f32x4{0,0,0,0}, f32x4{0,0,0,0}, f32x4{0,0,0,0}, f32x4{0,0,0,0}};
    float m[4] = {-1e30f, -1e30f, -1e30f, -1e30f};
    float l[4] = {0.0f, 0.0f, 0.0f, 0.0f};

    for (int k0 = 0; k0 < Sc; k0 += TK) {
        __syncthreads();
        #pragma unroll
        for (int u = 0; u < 2; ++u) {
            const int idx = t + u * 256;
            const int r = idx >> 3, cc = (idx & 7) * 8;
            *reinterpret_cast<uint4*>(&KsH[r][cc]) =
                *reinterpret_cast<const uint4*>(Khi + kbase + (size_t)(k0 + r) * DKc + cc);
            *reinterpret_cast<uint4*>(&KsL[r][cc]) =
                *reinterpret_cast<const uint4*>(Klo + kbase + (size_t)(k0 + r) * DKc + cc);
            *reinterpret_cast<uint4*>(&Vs[r][cc]) =
                *reinterpret_cast<const uint4*>(Vtg + vbase + (size_t)r * Sc + k0 + cc);
        }
        if (t < TK) mk[t] = mb[k0 + t];
        __syncthreads();

        float sc[4][4];
        #pragma unroll
        for (int n = 0; n < 4; ++n) {
            const bf16x8 bh0 = *reinterpret_cast<const bf16x8*>(&KsH[n * 16 + li][lg * 8]);
            const bf16x8 bh1 = *reinterpret_cast<const bf16x8*>(&KsH[n * 16 + li][32 + lg * 8]);
            const bf16x8 bl0 = *reinterpret_cast<const bf16x8*>(&KsL[n * 16 + li][lg * 8]);
            const bf16x8 bl1 = *reinterpret_cast<const bf16x8*>(&KsL[n * 16 + li][32 + lg * 8]);
            f32x4 a = {0, 0, 0, 0};
            a = __builtin_amdgcn_mfma_f32_16x16x32_bf16(qh0, bh0, a, 0, 0, 0);
            a = __builtin_amdgcn_mfma_f32_16x16x32_bf16(qh1, bh1, a, 0, 0, 0);
            a = __builtin_amdgcn_mfma_f32_16x16x32_bf16(qh0, bl0, a, 0, 0, 0);
            a = __builtin_amdgcn_mfma_f32_16x16x32_bf16(qh1, bl1, a, 0, 0, 0);
            a = __builtin_amdgcn_mfma_f32_16x16x32_bf16(ql0, bh0, a, 0, 0, 0);
            a = __builtin_amdgcn_mfma_f32_16x16x32_bf16(ql1, bh1, a, 0, 0, 0);
            const float mz = mk[n * 16 + li] ? 0.0f : INFTY;
            #pragma unroll
            for (int r = 0; r < 4; ++r) sc[n][r] = a[r] * 0.125f - mz;
        }

        float mx[4], rs[4], sum[4];
        #pragma unroll
        for (int r = 0; r < 4; ++r)
            mx[r] = fmaxf(fmaxf(sc[0][r], sc[1][r]), fmaxf(sc[2][r], sc[3][r]));
        #pragma unroll
        for (int o = 1; o < 16; o <<= 1)
            #pragma unroll
            for (int r = 0; r < 4; ++r) mx[r] = fmaxf(mx[r], __shfl_xor(mx[r], o));
        #pragma unroll
        for (int r = 0; r < 4; ++r) {
            const float mn = fmaxf(m[r], mx[r]);
            rs[r] = __expf(m[r] - mn);
            m[r]  = mn;
            sum[r] = 0.0f;
        }
        #pragma unroll
        for (int n = 0; n < 4; ++n)
            #pragma unroll
            for (int r = 0; r < 4; ++r) {
                const float p = __expf(sc[n][r] - m[r]);
                sc[n][r] = p;
                sum[r] += p;
            }
        #pragma unroll
        for (int o = 1; o < 16; o <<= 1)
            #pragma unroll
            for (int r = 0; r < 4; ++r) sum[r] += __shfl_xor(sum[r], o);
        #pragma unroll
        for (int r = 0; r < 4; ++r) l[r] = l[r] * rs[r] + sum[r];

        #pragma unroll
        for (int n = 0; n < 4; ++n)
            #pragma unroll
            for (int r = 0; r < 4; ++r)
                Ps[wave * 16 + lg * 4 + r][li + 16 * n] = bf16_rn(sc[n][r]);

        #pragma unroll
        for (int dt = 0; dt < 4; ++dt)
            #pragma unroll
            for (int r = 0; r < 4; ++r) accO[dt][r] *= rs[r];

        #pragma unroll
        for (int c = 0; c < 2; ++c) {
            const bf16x8 pa = *reinterpret_cast<const bf16x8*>(&Ps[wave * 16 + li][c * 32 + lg * 8]);
            #pragma unroll
            for (int dt = 0; dt < 4; ++dt) {
                const bf16x8 vb = *reinterpret_cast<const bf16x8*>(&Vs[dt * 16 + li][c * 32 + lg * 8]);
                accO[dt] = __builtin_amdgcn_mfma_f32_16x16x32_bf16(pa, vb, accO[dt], 0, 0, 0);
            }
        }
    }

    float inv[4];
    #pragma unroll
    for (int r = 0; r < 4; ++r) inv[r] = 1.0f / l[r];
    #pragma unroll
    for (int dt = 0; dt < 4; ++dt)
        #pragma unroll
        for (int r = 0; r < 4; ++r) {
            const int q = q0 + wave * 16 + lg * 4 + r;
            const size_t o = (size_t)(b * Sc + q) * Dc + h * DKc + li + 16 * dt;
            const float val = accO[dt][r] * inv[r];
            const unsigned short hi = bf16_rn(val);
            atthi[o] = hi;
            attlo[o] = bf16_rn(val - __uint_as_float((uint32_t)hi << 16));
        }
}

// ---------------------------------------------------------------------------
extern "C" void kernel_launch(void* const* d_in, const int* in_sizes, int n_in,
                              void* d_out, int out_size, void* d_ws, size_t ws_size,
                              hipStream_t stream) {
    const float* x    = (const float*)d_in[0];
    const void*  mraw = d_in[1];
    const float* WQ   = (const float*)d_in[2];
    const float* WK   = (const float*)d_in[3];
    const float* WV   = (const float*)d_in[4];
    const float* WO   = (const float*)d_in[5];
    float* out = (float*)d_out;

    // ws: mask(32KB) | xhi,xlo (2x16.78MB, later aliased as atthi/attlo)
    //   | 7 x W^T bf16 (2MB each) | Qhi,Qlo,Khi,Klo,Vt (5x16.78MB)  = 132.2MB
    int* mi = (int*)d_ws;
    const size_t SZ = (size_t)Mtot * Dc;
    const size_t WSZ = (size_t)Dc * Dc;
    unsigned short* xhi = (unsigned short*)((char*)d_ws + 32768);
    unsigned short* xlo = xhi + SZ;
    unsigned short* WQh = xlo + SZ;
    unsigned short* WQl = WQh + WSZ;
    unsigned short* WKh = WQh + 2 * WSZ;
    unsigned short* WKl = WQh + 3 * WSZ;
    unsigned short* WVh = WQh + 4 * WSZ;
    unsigned short* WOh = WQh + 5 * WSZ;
    unsigned short* WOl = WQh + 6 * WSZ;
    unsigned short* Qhi = WQh + 7 * WSZ;
    unsigned short* Qlo = Qhi + SZ;
    unsigned short* Khi = Qhi + 2 * SZ;
    unsigned short* Klo = Qhi + 3 * SZ;
    unsigned short* Vt  = Qhi + 4 * SZ;
    unsigned short* atthi = xhi;   // alias: x split is dead after projections
    unsigned short* attlo = xlo;

    mask_norm<<<1, 256, 0, stream>>>(mraw, mi);
    split_x<<<(int)(SZ / 1024), 256, 0, stream>>>(x, xhi, xlo);
    const dim3 gW(16, 16);
    split_wt<true ><<<gW, 256, 0, stream>>>(WQ, WQh, WQl);
    split_wt<true ><<<gW, 256, 0, stream>>>(WK, WKh, WKl);
    split_wt<false><<<gW, 256, 0, stream>>>(WV, WVh, nullptr);
    split_wt<true ><<<gW, 256, 0, stream>>>(WO, WOh, WOl);

    const dim3 gG(Dc / 128, Mtot / 128);   // (8, 64)
    gemm_mfma<3, 0><<<gG, 256, 0, stream>>>(xhi, xlo, WQh, WQl, nullptr, Qhi, Qlo, nullptr);
    gemm_mfma<3, 0><<<gG, 256, 0, stream>>>(xhi, xlo, WKh, WKl, nullptr, Khi, Klo, nullptr);
    gemm_mfma<1, 1><<<gG, 256, 0, stream>>>(xhi, nullptr, WVh, nullptr, nullptr, Vt, nullptr, nullptr);

    attn_mfma<<<dim3(Sc / 64, Bc * Hc), 256, 0, stream>>>(Qhi, Qlo, Khi, Klo, Vt, mi, atthi, attlo);

    gemm_mfma<3, 2><<<gG, 256, 0, stream>>>(atthi, attlo, WOh, WOl, mi, nullptr, nullptr, out);
}

// Round 7
// 558.482 us; speedup vs baseline: 5.0274x; 1.0072x over previous
//
#include <hip/hip_runtime.h>
#include <hip/hip_bf16.h>
#include <cstdint>
#include <cstddef>

constexpr int Bc  = 4;
constexpr int Sc  = 2048;
constexpr int Dc  = 1024;
constexpr int Hc  = 16;
constexpr int DKc = 64;
constexpr int Mtot = Bc * Sc;              // 8192 rows
constexpr float SC2  = 0.125f * 1.4426950408889634f;   // 1/sqrt(64) * log2(e)
constexpr float INF2 = 1000000.0f * 1.4426950408889634f;

typedef short bf16x8 __attribute__((ext_vector_type(8)));
typedef float f32x4  __attribute__((ext_vector_type(4)));

__device__ inline unsigned short bf16_rn(float f) {
    uint32_t u = __float_as_uint(f);
    uint32_t r = (u + 0x7FFFu + ((u >> 16) & 1u)) >> 16;
    return (unsigned short)r;
}

// ---------------------------------------------------------------------------
// Kernel 0: normalize padding mask to int32[8192] regardless of shipped dtype.
// ---------------------------------------------------------------------------
__global__ __launch_bounds__(256) void mask_norm(const void* __restrict__ mraw,
                                                 int* __restrict__ mi) {
    __shared__ int fF32, fU8, fI32;
    if (threadIdx.x == 0) { fF32 = 0; fU8 = 0; fI32 = 0; }
    __syncthreads();
    const unsigned char* mb = (const unsigned char*)mraw;
    int aF = 0, a1 = 0, a4 = 0;
    for (int i = threadIdx.x; i < Mtot; i += 256) {
        unsigned char v = mb[i];
        if ((i & 3) == 3 && v == 0x3F) aF = 1;
        if (v) {
            if (i & 3) a1 = 1;
            else if (i & 7) a4 = 1;
        }
    }
    if (aF) fF32 = 1;
    if (a1) fU8 = 1;
    if (a4) fI32 = 1;
    __syncthreads();
    if (fF32) {
        const float* mf = (const float*)mraw;
        for (int s = threadIdx.x; s < Mtot; s += 256) mi[s] = (mf[s] != 0.0f);
    } else if (fU8) {
        for (int s = threadIdx.x; s < Mtot; s += 256) mi[s] = (mb[s] != 0);
    } else if (fI32) {
        const int* m32 = (const int*)mraw;
        for (int s = threadIdx.x; s < Mtot; s += 256) mi[s] = (m32[s] != 0);
    } else {
        const long long* m64 = (const long long*)mraw;
        for (int s = threadIdx.x; s < Mtot; s += 256) mi[s] = (m64[s] != 0);
    }
}

// ---------------------------------------------------------------------------
// Kernel P1: split x (f32) -> xhi + xlo (bf16), row-major [M][D].
// ---------------------------------------------------------------------------
__global__ __launch_bounds__(256) void split_x(const float* __restrict__ x,
                                               unsigned short* __restrict__ xhi,
                                               unsigned short* __restrict__ xlo) {
    const int i = (blockIdx.x * 256 + threadIdx.x) * 4;
    float4 v = *reinterpret_cast<const float4*>(x + i);
    ushort4 h, l;
    h.x = bf16_rn(v.x); l.x = bf16_rn(v.x - __uint_as_float((uint32_t)h.x << 16));
    h.y = bf16_rn(v.y); l.y = bf16_rn(v.y - __uint_as_float((uint32_t)h.y << 16));
    h.z = bf16_rn(v.z); l.z = bf16_rn(v.z - __uint_as_float((uint32_t)h.z << 16));
    h.w = bf16_rn(v.w); l.w = bf16_rn(v.w - __uint_as_float((uint32_t)h.w << 16));
    *reinterpret_cast<ushort4*>(xhi + i) = h;
    *reinterpret_cast<ushort4*>(xlo + i) = l;
}

// ---------------------------------------------------------------------------
// Kernel P2: split + transpose W (f32 [K][N]) -> WhT (+WlT) bf16 [N][K].
// ---------------------------------------------------------------------------
template<bool WLO>
__global__ __launch_bounds__(256) void split_wt(const float* __restrict__ W,
                                                unsigned short* __restrict__ WhT,
                                                unsigned short* __restrict__ WlT) {
    __shared__ float ls[64][68];
    const int k0 = blockIdx.y * 64, n0 = blockIdx.x * 64;
    const int t = threadIdx.x;
    #pragma unroll
    for (int l = 0; l < 4; ++l) {
        const int idx = t + l * 256;
        const int r = idx >> 4, c = (idx & 15) * 4;
        *reinterpret_cast<float4*>(&ls[r][c]) =
            *reinterpret_cast<const float4*>(W + (size_t)(k0 + r) * Dc + n0 + c);
    }
    __syncthreads();
    #pragma unroll
    for (int l = 0; l < 4; ++l) {
        const int idx = t + l * 256;
        const int on = idx >> 4, kq = (idx & 15) * 4;
        float v0 = ls[kq + 0][on], v1 = ls[kq + 1][on], v2 = ls[kq + 2][on], v3 = ls[kq + 3][on];
        ushort4 h;
        h.x = bf16_rn(v0); h.y = bf16_rn(v1); h.z = bf16_rn(v2); h.w = bf16_rn(v3);
        *reinterpret_cast<ushort4*>(WhT + (size_t)(n0 + on) * Dc + k0 + kq) = h;
        if (WLO) {
            ushort4 lo;
            lo.x = bf16_rn(v0 - __uint_as_float((uint32_t)h.x << 16));
            lo.y = bf16_rn(v1 - __uint_as_float((uint32_t)h.y << 16));
            lo.z = bf16_rn(v2 - __uint_as_float((uint32_t)h.z << 16));
            lo.w = bf16_rn(v3 - __uint_as_float((uint32_t)h.w << 16));
            *reinterpret_cast<ushort4*>(WlT + (size_t)(n0 + on) * Dc + k0 + kq) = lo;
        }
    }
}

// ---------------------------------------------------------------------------
// Kernel G: split-bf16 MFMA GEMM, 128x128 tile, 4 waves (2x2 of 64x64),
// BK=32. A=[M][K] (hi,lo), B=W^T=[N][K] (hi,lo).
// NTERMS=1: AH*BH.  NTERMS=3: + AH*BL + AL*BH (f32-equivalent).
// EPI: 0 = split-head hi/lo ([bh][s][dk]); 1 = V^T bf16 ([bh][dk][s]);
//      2 = mask+abs+f32 out.
// ---------------------------------------------------------------------------
template<int NTERMS, int EPI>
__global__ __launch_bounds__(256) void gemm_mfma(
    const unsigned short* __restrict__ Ahi, const unsigned short* __restrict__ Alo,
    const unsigned short* __restrict__ Bhi, const unsigned short* __restrict__ Blo,
    const int* __restrict__ mask,
    unsigned short* __restrict__ O1, unsigned short* __restrict__ O2,
    float* __restrict__ Of) {
    __shared__ __align__(16) unsigned short Ah[128][40];
    __shared__ __align__(16) unsigned short Al[128][40];
    __shared__ __align__(16) unsigned short Bh[128][40];
    __shared__ __align__(16) unsigned short Bl[128][40];
    const int t = threadIdx.x;
    const int n0 = blockIdx.x * 128, m0 = blockIdx.y * 128;
    const int wave = t >> 6, lane = t & 63, li = lane & 15, lg = lane >> 4;
    const int wm = (wave >> 1) * 64, wn = (wave & 1) * 64;
    const int srow = t >> 1, sh = (t & 1) * 16;

    f32x4 acc[4][4] = {};

    for (int k0 = 0; k0 < Dc; k0 += 32) {
        __syncthreads();
        {
            const size_t ga = (size_t)(m0 + srow) * Dc + k0 + sh;
            const size_t gb = (size_t)(n0 + srow) * Dc + k0 + sh;
            *reinterpret_cast<uint4*>(&Ah[srow][sh])     = *reinterpret_cast<const uint4*>(Ahi + ga);
            *reinterpret_cast<uint4*>(&Ah[srow][sh + 8]) = *reinterpret_cast<const uint4*>(Ahi + ga + 8);
            *reinterpret_cast<uint4*>(&Bh[srow][sh])     = *reinterpret_cast<const uint4*>(Bhi + gb);
            *reinterpret_cast<uint4*>(&Bh[srow][sh + 8]) = *reinterpret_cast<const uint4*>(Bhi + gb + 8);
            if (NTERMS == 3) {
                *reinterpret_cast<uint4*>(&Al[srow][sh])     = *reinterpret_cast<const uint4*>(Alo + ga);
                *reinterpret_cast<uint4*>(&Al[srow][sh + 8]) = *reinterpret_cast<const uint4*>(Alo + ga + 8);
                *reinterpret_cast<uint4*>(&Bl[srow][sh])     = *reinterpret_cast<const uint4*>(Blo + gb);
                *reinterpret_cast<uint4*>(&Bl[srow][sh + 8]) = *reinterpret_cast<const uint4*>(Blo + gb + 8);
            }
        }
        __syncthreads();

        bf16x8 bhf[4], blf[4];
        #pragma unroll
        for (int ni = 0; ni < 4; ++ni) {
            bhf[ni] = *reinterpret_cast<const bf16x8*>(&Bh[wn + ni * 16 + li][lg * 8]);
            if (NTERMS == 3)
                blf[ni] = *reinterpret_cast<const bf16x8*>(&Bl[wn + ni * 16 + li][lg * 8]);
        }
        #pragma unroll
        for (int mi = 0; mi < 4; ++mi) {
            const bf16x8 ahf = *reinterpret_cast<const bf16x8*>(&Ah[wm + mi * 16 + li][lg * 8]);
            bf16x8 alf = {};
            if (NTERMS == 3)
                alf = *reinterpret_cast<const bf16x8*>(&Al[wm + mi * 16 + li][lg * 8]);
            #pragma unroll
            for (int ni = 0; ni < 4; ++ni) {
                acc[mi][ni] = __builtin_amdgcn_mfma_f32_16x16x32_bf16(ahf, bhf[ni], acc[mi][ni], 0, 0, 0);
                if (NTERMS == 3) {
                    acc[mi][ni] = __builtin_amdgcn_mfma_f32_16x16x32_bf16(ahf, blf[ni], acc[mi][ni], 0, 0, 0);
                    acc[mi][ni] = __builtin_amdgcn_mfma_f32_16x16x32_bf16(alf, bhf[ni], acc[mi][ni], 0, 0, 0);
                }
            }
        }
    }

    #pragma unroll
    for (int mi = 0; mi < 4; ++mi) {
        #pragma unroll
        for (int r = 0; r < 4; ++r) {
            const int m = m0 + wm + mi * 16 + lg * 4 + r;
            #pragma unroll
            for (int ni = 0; ni < 4; ++ni) {
                const int n = n0 + wn + ni * 16 + li;
                const float v = acc[mi][ni][r];
                if (EPI == 0) {
                    const int b = m >> 11, s = m & 2047, h = n & 15, dk = n >> 4;
                    const size_t o = ((size_t)(b * Hc + h) * Sc + s) * DKc + dk;
                    const unsigned short hi = bf16_rn(v);
                    O1[o] = hi;
                    O2[o] = bf16_rn(v - __uint_as_float((uint32_t)hi << 16));
                } else if (EPI == 1) {
                    const int b = m >> 11, s = m & 2047, h = n & 15, dk = n >> 4;
                    O1[((size_t)(b * Hc + h) * DKc + dk) * Sc + s] = bf16_rn(v);
                } else {
                    Of[(size_t)m * Dc + n] = mask[m] ? fabsf(v) : 0.0f;
                }
            }
        }
    }
}

// ---------------------------------------------------------------------------
// Kernel 2: MFMA flash attention v3.
// 4 waves x 32 q-rows = 128-row q-block; TK=64; 3-term split-bf16 QK;
// bf16 PV with a ones-column V tile computing l via MFMA (no sum shuffles).
// exp2-domain softmax.  Grid: 1024 blocks, XCD-swizzled (8 heads/XCD).
// att out: bf16 [b][s][h*64+dk].
// ---------------------------------------------------------------------------
__global__ __launch_bounds__(256) void attn_mfma(const unsigned short* __restrict__ Qhi,
                                                 const unsigned short* __restrict__ Qlo,
                                                 const unsigned short* __restrict__ Khi,
                                                 const unsigned short* __restrict__ Klo,
                                                 const unsigned short* __restrict__ Vtg,
                                                 const int*   __restrict__ mask,
                                                 unsigned short* __restrict__ att) {
    constexpr int TK = 64;
    const int id  = blockIdx.x;
    const int swz = (id & 7) * 128 + (id >> 3);     // bijective: 1024 % 8 == 0
    const int qb  = swz & 15;
    const int bh  = swz >> 4;
    const int b = bh >> 4, h = bh & 15;
    const int q0 = qb * 128;
    const int* mb = mask + b * Sc;

    __shared__ __align__(16) unsigned short KsH[64][72];
    __shared__ __align__(16) unsigned short KsL[64][72];
    __shared__ __align__(16) unsigned short Vs[80][72];    // rows 64..79: ones-column tile
    __shared__ __align__(16) unsigned short Ps[128][72];
    __shared__ int mk[TK];

    const int t    = threadIdx.x;
    const int wave = t >> 6;
    const int lane = t & 63;
    const int lg   = lane >> 4;
    const int li   = lane & 15;

    // init the constant V extension rows once: row 64 = 1.0, rows 65..79 = 0
    {
        const int r = 64 + (t >> 4), c4 = (t & 15) * 4;
        const unsigned short val = ((t >> 4) == 0) ? (unsigned short)0x3F80 : (unsigned short)0;
        ushort4 v; v.x = val; v.y = val; v.z = val; v.w = val;
        *reinterpret_cast<ushort4*>(&Vs[r][c4]) = v;
    }

    // Q A-fragments for 2 halves (rows wave*32 + half*16 + li)
    bf16x8 qh[2][2], ql[2][2];
    #pragma unroll
    for (int hf = 0; hf < 2; ++hf) {
        const size_t qrow = ((size_t)bh * Sc + q0 + wave * 32 + hf * 16 + li) * DKc + lg * 8;
        qh[hf][0] = *reinterpret_cast<const bf16x8*>(Qhi + qrow);
        qh[hf][1] = *reinterpret_cast<const bf16x8*>(Qhi + qrow + 32);
        ql[hf][0] = *reinterpret_cast<const bf16x8*>(Qlo + qrow);
        ql[hf][1] = *reinterpret_cast<const bf16x8*>(Qlo + qrow + 32);
    }

    const size_t kbase = (size_t)bh * Sc * DKc;
    const size_t vbase = (size_t)bh * DKc * Sc;

    f32x4 accO[2][5] = {};
    float m[2][4];
    #pragma unroll
    for (int hf = 0; hf < 2; ++hf)
        #pragma unroll
        for (int r = 0; r < 4; ++r) m[hf][r] = -1e30f;

    for (int k0 = 0; k0 < Sc; k0 += TK) {
        __syncthreads();
        #pragma unroll
        for (int u = 0; u < 2; ++u) {
            const int idx = t + u * 256;
            const int r = idx >> 3, cc = (idx & 7) * 8;
            *reinterpret_cast<uint4*>(&KsH[r][cc]) =
                *reinterpret_cast<const uint4*>(Khi + kbase + (size_t)(k0 + r) * DKc + cc);
            *reinterpret_cast<uint4*>(&KsL[r][cc]) =
                *reinterpret_cast<const uint4*>(Klo + kbase + (size_t)(k0 + r) * DKc + cc);
            *reinterpret_cast<uint4*>(&Vs[r][cc]) =
                *reinterpret_cast<const uint4*>(Vtg + vbase + (size_t)r * Sc + k0 + cc);
        }
        if (t < TK) mk[t] = mb[k0 + t];
        __syncthreads();

        // ---- QK^T (both halves share the K fragments) -------------------
        float sc[2][4][4];
        #pragma unroll
        for (int n = 0; n < 4; ++n) {
            const bf16x8 bh0 = *reinterpret_cast<const bf16x8*>(&KsH[n * 16 + li][lg * 8]);
            const bf16x8 bh1 = *reinterpret_cast<const bf16x8*>(&KsH[n * 16 + li][32 + lg * 8]);
            const bf16x8 bl0 = *reinterpret_cast<const bf16x8*>(&KsL[n * 16 + li][lg * 8]);
            const bf16x8 bl1 = *reinterpret_cast<const bf16x8*>(&KsL[n * 16 + li][32 + lg * 8]);
            const float mz = mk[n * 16 + li] ? 0.0f : INF2;
            #pragma unroll
            for (int hf = 0; hf < 2; ++hf) {
                f32x4 a = {0, 0, 0, 0};
                a = __builtin_amdgcn_mfma_f32_16x16x32_bf16(qh[hf][0], bh0, a, 0, 0, 0);
                a = __builtin_amdgcn_mfma_f32_16x16x32_bf16(qh[hf][1], bh1, a, 0, 0, 0);
                a = __builtin_amdgcn_mfma_f32_16x16x32_bf16(qh[hf][0], bl0, a, 0, 0, 0);
                a = __builtin_amdgcn_mfma_f32_16x16x32_bf16(qh[hf][1], bl1, a, 0, 0, 0);
                a = __builtin_amdgcn_mfma_f32_16x16x32_bf16(ql[hf][0], bh0, a, 0, 0, 0);
                a = __builtin_amdgcn_mfma_f32_16x16x32_bf16(ql[hf][1], bh1, a, 0, 0, 0);
                #pragma unroll
                for (int r = 0; r < 4; ++r) sc[hf][n][r] = a[r] * SC2 - mz;
            }
        }

        // ---- row max (shfl over 16 li-lanes), exp2, pack P --------------
        float mx[2][4], rs[2][4];
        #pragma unroll
        for (int hf = 0; hf < 2; ++hf)
            #pragma unroll
            for (int r = 0; r < 4; ++r)
                mx[hf][r] = fmaxf(fmaxf(sc[hf][0][r], sc[hf][1][r]),
                                  fmaxf(sc[hf][2][r], sc[hf][3][r]));
        #pragma unroll
        for (int o = 1; o < 16; o <<= 1)
            #pragma unroll
            for (int hf = 0; hf < 2; ++hf)
                #pragma unroll
                for (int r = 0; r < 4; ++r)
                    mx[hf][r] = fmaxf(mx[hf][r], __shfl_xor(mx[hf][r], o));
        #pragma unroll
        for (int hf = 0; hf < 2; ++hf)
            #pragma unroll
            for (int r = 0; r < 4; ++r) {
                const float mn = fmaxf(m[hf][r], mx[hf][r]);
                rs[hf][r] = exp2f(m[hf][r] - mn);
                m[hf][r]  = mn;
            }
        #pragma unroll
        for (int hf = 0; hf < 2; ++hf)
            #pragma unroll
            for (int n = 0; n < 4; ++n)
                #pragma unroll
                for (int r = 0; r < 4; ++r)
                    Ps[wave * 32 + hf * 16 + lg * 4 + r][li + 16 * n] =
                        bf16_rn(exp2f(sc[hf][n][r] - m[hf][r]));

        // rescale all accumulators (incl. the l-tile dt=4)
        #pragma unroll
        for (int hf = 0; hf < 2; ++hf)
            #pragma unroll
            for (int dt = 0; dt < 5; ++dt)
                #pragma unroll
                for (int r = 0; r < 4; ++r)
                    accO[hf][dt][r] *= rs[hf][r];

        // ---- PV (wave-local Ps; V frags shared across halves) -----------
        #pragma unroll
        for (int c = 0; c < 2; ++c) {
            bf16x8 pa[2];
            #pragma unroll
            for (int hf = 0; hf < 2; ++hf)
                pa[hf] = *reinterpret_cast<const bf16x8*>(&Ps[wave * 32 + hf * 16 + li][c * 32 + lg * 8]);
            #pragma unroll
            for (int dt = 0; dt < 5; ++dt) {
                const bf16x8 vb = *reinterpret_cast<const bf16x8*>(&Vs[dt * 16 + li][c * 32 + lg * 8]);
                #pragma unroll
                for (int hf = 0; hf < 2; ++hf)
                    accO[hf][dt] = __builtin_amdgcn_mfma_f32_16x16x32_bf16(pa[hf], vb, accO[hf][dt], 0, 0, 0);
            }
        }
    }

    // l lives in column 0 of the dt=4 tile (li==0 lanes); broadcast + write
    #pragma unroll
    for (int hf = 0; hf < 2; ++hf) {
        float inv[4];
        #pragma unroll
        for (int r = 0; r < 4; ++r) {
            const float lb = __shfl(accO[hf][4][r], lane & 0x30);
            inv[r] = 1.0f / lb;
        }
        #pragma unroll
        for (int dt = 0; dt < 4; ++dt)
            #pragma unroll
            for (int r = 0; r < 4; ++r) {
                const int q = q0 + wave * 32 + hf * 16 + lg * 4 + r;
                att[(size_t)(b * Sc + q) * Dc + h * DKc + li + 16 * dt] =
                    bf16_rn(accO[hf][dt][r] * inv[r]);
            }
    }
}

// ---------------------------------------------------------------------------
extern "C" void kernel_launch(void* const* d_in, const int* in_sizes, int n_in,
                              void* d_out, int out_size, void* d_ws, size_t ws_size,
                              hipStream_t stream) {
    const float* x    = (const float*)d_in[0];
    const void*  mraw = d_in[1];
    const float* WQ   = (const float*)d_in[2];
    const float* WK   = (const float*)d_in[3];
    const float* WV   = (const float*)d_in[4];
    const float* WO   = (const float*)d_in[5];
    float* out = (float*)d_out;

    // ws: mask(32KB) | xhi,xlo (2xSZ, xhi later aliased as att)
    //   | WQh,WQl,WKh,WKl,WVh,WOh (6 x WSZ) | Qhi,Qlo,Khi,Klo,Vt (5 x SZ)
    int* mi = (int*)d_ws;
    const size_t SZ = (size_t)Mtot * Dc;
    const size_t WSZ = (size_t)Dc * Dc;
    unsigned short* xhi = (unsigned short*)((char*)d_ws + 32768);
    unsigned short* xlo = xhi + SZ;
    unsigned short* WQh = xlo + SZ;
    unsigned short* WQl = WQh + WSZ;
    unsigned short* WKh = WQh + 2 * WSZ;
    unsigned short* WKl = WQh + 3 * WSZ;
    unsigned short* WVh = WQh + 4 * WSZ;
    unsigned short* WOh = WQh + 5 * WSZ;
    unsigned short* Qhi = WQh + 6 * WSZ;
    unsigned short* Qlo = Qhi + SZ;
    unsigned short* Khi = Qhi + 2 * SZ;
    unsigned short* Klo = Qhi + 3 * SZ;
    unsigned short* Vt  = Qhi + 4 * SZ;
    unsigned short* att = xhi;     // alias: x split dead after projections

    mask_norm<<<1, 256, 0, stream>>>(mraw, mi);
    split_x<<<(int)(SZ / 1024), 256, 0, stream>>>(x, xhi, xlo);
    const dim3 gW(16, 16);
    split_wt<true ><<<gW, 256, 0, stream>>>(WQ, WQh, WQl);
    split_wt<true ><<<gW, 256, 0, stream>>>(WK, WKh, WKl);
    split_wt<false><<<gW, 256, 0, stream>>>(WV, WVh, nullptr);
    split_wt<false><<<gW, 256, 0, stream>>>(WO, WOh, nullptr);

    const dim3 gG(Dc / 128, Mtot / 128);   // (8, 64)
    gemm_mfma<3, 0><<<gG, 256, 0, stream>>>(xhi, xlo, WQh, WQl, nullptr, Qhi, Qlo, nullptr);
    gemm_mfma<3, 0><<<gG, 256, 0, stream>>>(xhi, xlo, WKh, WKl, nullptr, Khi, Klo, nullptr);
    gemm_mfma<1, 1><<<gG, 256, 0, stream>>>(xhi, nullptr, WVh, nullptr, nullptr, Vt, nullptr, nullptr);

    attn_mfma<<<dim3(1024), 256, 0, stream>>>(Qhi, Qlo, Khi, Klo, Vt, mi, att);

    gemm_mfma<1, 2><<<gG, 256, 0, stream>>>(att, nullptr, WOh, nullptr, mi, nullptr, nullptr, out);
}

// Round 8
// 553.491 us; speedup vs baseline: 5.0727x; 1.0090x over previous
//
#include <hip/hip_runtime.h>
#include <hip/hip_bf16.h>
#include <cstdint>
#include <cstddef>

constexpr int Bc  = 4;
constexpr int Sc  = 2048;
constexpr int Dc  = 1024;
constexpr int Hc  = 16;
constexpr int DKc = 64;
constexpr int Mtot = Bc * Sc;              // 8192 rows
constexpr float SC2  = 0.125f * 1.4426950408889634f;   // 1/sqrt(64) * log2(e)
constexpr float INF2 = 1000000.0f * 1.4426950408889634f;

typedef short bf16x8 __attribute__((ext_vector_type(8)));
typedef float f32x4  __attribute__((ext_vector_type(4)));

__device__ inline unsigned short bf16_rn(float f) {
    uint32_t u = __float_as_uint(f);
    uint32_t r = (u + 0x7FFFu + ((u >> 16) & 1u)) >> 16;
    return (unsigned short)r;
}
// pack two f32 -> two bf16 in one u32 (D[15:0]=S0, D[31:16]=S1)
__device__ inline uint32_t pk_bf16(float a, float b) {
    uint32_t d;
    asm("v_cvt_pk_bf16_f32 %0, %1, %2" : "=v"(d) : "v"(a), "v"(b));
    return d;
}
// key permutation within a 64-block: k -> (k&15)*4 + (k>>4)&3  (bijective)
__device__ inline int perm64(int k) {
    return (k & ~63) | (((k & 15) << 2) | ((k >> 4) & 3));
}

// ---------------------------------------------------------------------------
// Kernel 0: normalize padding mask to int32[8192] regardless of shipped dtype.
// ---------------------------------------------------------------------------
__global__ __launch_bounds__(256) void mask_norm(const void* __restrict__ mraw,
                                                 int* __restrict__ mi) {
    __shared__ int fF32, fU8, fI32;
    if (threadIdx.x == 0) { fF32 = 0; fU8 = 0; fI32 = 0; }
    __syncthreads();
    const unsigned char* mb = (const unsigned char*)mraw;
    int aF = 0, a1 = 0, a4 = 0;
    for (int i = threadIdx.x; i < Mtot; i += 256) {
        unsigned char v = mb[i];
        if ((i & 3) == 3 && v == 0x3F) aF = 1;
        if (v) {
            if (i & 3) a1 = 1;
            else if (i & 7) a4 = 1;
        }
    }
    if (aF) fF32 = 1;
    if (a1) fU8 = 1;
    if (a4) fI32 = 1;
    __syncthreads();
    if (fF32) {
        const float* mf = (const float*)mraw;
        for (int s = threadIdx.x; s < Mtot; s += 256) mi[s] = (mf[s] != 0.0f);
    } else if (fU8) {
        for (int s = threadIdx.x; s < Mtot; s += 256) mi[s] = (mb[s] != 0);
    } else if (fI32) {
        const int* m32 = (const int*)mraw;
        for (int s = threadIdx.x; s < Mtot; s += 256) mi[s] = (m32[s] != 0);
    } else {
        const long long* m64 = (const long long*)mraw;
        for (int s = threadIdx.x; s < Mtot; s += 256) mi[s] = (m64[s] != 0);
    }
}

// ---------------------------------------------------------------------------
// Kernel P1: split x (f32) -> xhi + xlo (bf16), row-major [M][D].
// ---------------------------------------------------------------------------
__global__ __launch_bounds__(256) void split_x(const float* __restrict__ x,
                                               unsigned short* __restrict__ xhi,
                                               unsigned short* __restrict__ xlo) {
    const int i = (blockIdx.x * 256 + threadIdx.x) * 4;
    float4 v = *reinterpret_cast<const float4*>(x + i);
    ushort4 h, l;
    h.x = bf16_rn(v.x); l.x = bf16_rn(v.x - __uint_as_float((uint32_t)h.x << 16));
    h.y = bf16_rn(v.y); l.y = bf16_rn(v.y - __uint_as_float((uint32_t)h.y << 16));
    h.z = bf16_rn(v.z); l.z = bf16_rn(v.z - __uint_as_float((uint32_t)h.z << 16));
    h.w = bf16_rn(v.w); l.w = bf16_rn(v.w - __uint_as_float((uint32_t)h.w << 16));
    *reinterpret_cast<ushort4*>(xhi + i) = h;
    *reinterpret_cast<ushort4*>(xlo + i) = l;
}

// ---------------------------------------------------------------------------
// Kernel P2: split + transpose W (f32 [K][N]) -> WhT (+WlT) bf16 [N][K].
// PERM: permute K within 64-blocks (for WO, matching att col' layout).
// ---------------------------------------------------------------------------
template<bool WLO, bool PERM>
__global__ __launch_bounds__(256) void split_wt(const float* __restrict__ W,
                                                unsigned short* __restrict__ WhT,
                                                unsigned short* __restrict__ WlT) {
    __shared__ float ls[64][68];
    const int k0 = blockIdx.y * 64, n0 = blockIdx.x * 64;
    const int t = threadIdx.x;
    #pragma unroll
    for (int l = 0; l < 4; ++l) {
        const int idx = t + l * 256;
        const int r = idx >> 4, c = (idx & 15) * 4;
        *reinterpret_cast<float4*>(&ls[r][c]) =
            *reinterpret_cast<const float4*>(W + (size_t)(k0 + r) * Dc + n0 + c);
    }
    __syncthreads();
    #pragma unroll
    for (int l = 0; l < 4; ++l) {
        const int idx = t + l * 256;
        const int on = idx >> 4, kq = (idx & 15) * 4;
        #pragma unroll
        for (int j = 0; j < 4; ++j) {
            const float v = ls[kq + j][on];
            const int k  = k0 + kq + j;
            const int kd = PERM ? perm64(k) : k;
            const unsigned short h = bf16_rn(v);
            WhT[(size_t)(n0 + on) * Dc + kd] = h;
            if (WLO)
                WlT[(size_t)(n0 + on) * Dc + kd] =
                    bf16_rn(v - __uint_as_float((uint32_t)h << 16));
        }
    }
}

// ---------------------------------------------------------------------------
// Kernel G: split-bf16 MFMA GEMM, 128x128 tile, 4 waves (2x2 of 64x64),
// BK=32. A=[M][K] (hi,lo), B=W^T=[N][K] (hi,lo).
// NTERMS=1: AH*BH (LDS = 2 tiles).  NTERMS=3: + AH*BL + AL*BH (4 tiles).
// EPI: 0 = split-head hi/lo ([bh][s][dk]), output scaled by `scale`;
//      1 = V^T bf16 ([bh][dk][s']) with s' key-permuted;
//      2 = mask+abs+f32 out.
// ---------------------------------------------------------------------------
template<int NTERMS, int EPI>
__global__ __launch_bounds__(256) void gemm_mfma(
    const unsigned short* __restrict__ Ahi, const unsigned short* __restrict__ Alo,
    const unsigned short* __restrict__ Bhi, const unsigned short* __restrict__ Blo,
    const int* __restrict__ mask, float scale,
    unsigned short* __restrict__ O1, unsigned short* __restrict__ O2,
    float* __restrict__ Of) {
    constexpr int TILE = 128 * 40;
    __shared__ __align__(16) unsigned short S[(NTERMS == 3 ? 4 : 2) * TILE];
    unsigned short* Ah = S;
    unsigned short* Al = S + TILE;                          // only if NTERMS==3
    unsigned short* Bh = S + (NTERMS == 3 ? 2 : 1) * TILE;
    unsigned short* Bl = S + 3 * TILE;                      // only if NTERMS==3
    const int t = threadIdx.x;
    const int n0 = blockIdx.x * 128, m0 = blockIdx.y * 128;
    const int wave = t >> 6, lane = t & 63, li = lane & 15, lg = lane >> 4;
    const int wm = (wave >> 1) * 64, wn = (wave & 1) * 64;
    const int srow = t >> 1, sh = (t & 1) * 16;

    f32x4 acc[4][4] = {};

    for (int k0 = 0; k0 < Dc; k0 += 32) {
        __syncthreads();
        {
            const size_t ga = (size_t)(m0 + srow) * Dc + k0 + sh;
            const size_t gb = (size_t)(n0 + srow) * Dc + k0 + sh;
            *reinterpret_cast<uint4*>(&Ah[srow * 40 + sh])     = *reinterpret_cast<const uint4*>(Ahi + ga);
            *reinterpret_cast<uint4*>(&Ah[srow * 40 + sh + 8]) = *reinterpret_cast<const uint4*>(Ahi + ga + 8);
            *reinterpret_cast<uint4*>(&Bh[srow * 40 + sh])     = *reinterpret_cast<const uint4*>(Bhi + gb);
            *reinterpret_cast<uint4*>(&Bh[srow * 40 + sh + 8]) = *reinterpret_cast<const uint4*>(Bhi + gb + 8);
            if (NTERMS == 3) {
                *reinterpret_cast<uint4*>(&Al[srow * 40 + sh])     = *reinterpret_cast<const uint4*>(Alo + ga);
                *reinterpret_cast<uint4*>(&Al[srow * 40 + sh + 8]) = *reinterpret_cast<const uint4*>(Alo + ga + 8);
                *reinterpret_cast<uint4*>(&Bl[srow * 40 + sh])     = *reinterpret_cast<const uint4*>(Blo + gb);
                *reinterpret_cast<uint4*>(&Bl[srow * 40 + sh + 8]) = *reinterpret_cast<const uint4*>(Blo + gb + 8);
            }
        }
        __syncthreads();

        bf16x8 bhf[4], blf[4];
        #pragma unroll
        for (int ni = 0; ni < 4; ++ni) {
            bhf[ni] = *reinterpret_cast<const bf16x8*>(&Bh[(wn + ni * 16 + li) * 40 + lg * 8]);
            if (NTERMS == 3)
                blf[ni] = *reinterpret_cast<const bf16x8*>(&Bl[(wn + ni * 16 + li) * 40 + lg * 8]);
        }
        #pragma unroll
        for (int mi = 0; mi < 4; ++mi) {
            const bf16x8 ahf = *reinterpret_cast<const bf16x8*>(&Ah[(wm + mi * 16 + li) * 40 + lg * 8]);
            bf16x8 alf = {};
            if (NTERMS == 3)
                alf = *reinterpret_cast<const bf16x8*>(&Al[(wm + mi * 16 + li) * 40 + lg * 8]);
            #pragma unroll
            for (int ni = 0; ni < 4; ++ni) {
                acc[mi][ni] = __builtin_amdgcn_mfma_f32_16x16x32_bf16(ahf, bhf[ni], acc[mi][ni], 0, 0, 0);
                if (NTERMS == 3) {
                    acc[mi][ni] = __builtin_amdgcn_mfma_f32_16x16x32_bf16(ahf, blf[ni], acc[mi][ni], 0, 0, 0);
                    acc[mi][ni] = __builtin_amdgcn_mfma_f32_16x16x32_bf16(alf, bhf[ni], acc[mi][ni], 0, 0, 0);
                }
            }
        }
    }

    #pragma unroll
    for (int mi = 0; mi < 4; ++mi) {
        #pragma unroll
        for (int r = 0; r < 4; ++r) {
            const int m = m0 + wm + mi * 16 + lg * 4 + r;
            #pragma unroll
            for (int ni = 0; ni < 4; ++ni) {
                const int n = n0 + wn + ni * 16 + li;
                const float v = acc[mi][ni][r];
                if (EPI == 0) {
                    const int b = m >> 11, s = m & 2047, h = n & 15, dk = n >> 4;
                    const size_t o = ((size_t)(b * Hc + h) * Sc + s) * DKc + dk;
                    const float vs = v * scale;
                    const unsigned short hi = bf16_rn(vs);
                    O1[o] = hi;
                    O2[o] = bf16_rn(vs - __uint_as_float((uint32_t)hi << 16));
                } else if (EPI == 1) {
                    const int b = m >> 11, s = m & 2047, h = n & 15, dk = n >> 4;
                    O1[((size_t)(b * Hc + h) * DKc + dk) * Sc + perm64(s)] = bf16_rn(v);
                } else {
                    Of[(size_t)m * Dc + n] = mask[m] ? fabsf(v) : 0.0f;
                }
            }
        }
    }
}

// ---------------------------------------------------------------------------
// Kernel 2: MFMA flash attention v4.
// 4 waves x 32 q-rows = 128-row q-block; TK=64; 3-term split-bf16 QK (Q
// pre-scaled by SC2); bf16 PV with ones-column V tile computing l via MFMA.
// P tile ALIASES the K tiles (dead after QK) -> LDS 30KB, ~2x occupancy.
// P packed with v_cvt_pk_bf16_f32, stored b64 in key-permuted cols (col' =
// (k&15)*4 + k>>4); V and WO are pre-permuted identically -> consistent.
// ---------------------------------------------------------------------------
__global__ __launch_bounds__(256) void attn_mfma(const unsigned short* __restrict__ Qhi,
                                                 const unsigned short* __restrict__ Qlo,
                                                 const unsigned short* __restrict__ Khi,
                                                 const unsigned short* __restrict__ Klo,
                                                 const unsigned short* __restrict__ Vtg,
                                                 const int*   __restrict__ mask,
                                                 unsigned short* __restrict__ att) {
    constexpr int TK = 64;
    const int id  = blockIdx.x;
    const int swz = (id & 7) * 128 + (id >> 3);     // bijective: 1024 % 8 == 0
    const int qb  = swz & 15;
    const int bh  = swz >> 4;
    const int b = bh >> 4, h = bh & 15;
    const int q0 = qb * 128;
    const int* mb = mask + b * Sc;

    // rows 0..63: K-hi, rows 64..127: K-lo; after QK the SAME space is Ps[128]
    __shared__ __align__(16) unsigned short PsKs[128][72];
    __shared__ __align__(16) unsigned short Vs[80][72];    // rows 64..79: ones-col tile
    __shared__ int mk[TK];

    const int t    = threadIdx.x;
    const int wave = t >> 6;
    const int lane = t & 63;
    const int lg   = lane >> 4;
    const int li   = lane & 15;

    // init constant V extension rows once: row 64 = 1.0, rows 65..79 = 0
    {
        const int r = 64 + (t >> 4), c4 = (t & 15) * 4;
        const unsigned short val = ((t >> 4) == 0) ? (unsigned short)0x3F80 : (unsigned short)0;
        ushort4 v; v.x = val; v.y = val; v.z = val; v.w = val;
        *reinterpret_cast<ushort4*>(&Vs[r][c4]) = v;
    }

    // Q A-fragments (pre-scaled by SC2 in projection): rows wave*32+hf*16+li
    bf16x8 qh[2][2], ql[2][2];
    #pragma unroll
    for (int hf = 0; hf < 2; ++hf) {
        const size_t qrow = ((size_t)bh * Sc + q0 + wave * 32 + hf * 16 + li) * DKc + lg * 8;
        qh[hf][0] = *reinterpret_cast<const bf16x8*>(Qhi + qrow);
        qh[hf][1] = *reinterpret_cast<const bf16x8*>(Qhi + qrow + 32);
        ql[hf][0] = *reinterpret_cast<const bf16x8*>(Qlo + qrow);
        ql[hf][1] = *reinterpret_cast<const bf16x8*>(Qlo + qrow + 32);
    }

    const size_t kbase = (size_t)bh * Sc * DKc;
    const size_t vbase = (size_t)bh * DKc * Sc;

    f32x4 accO[2][5] = {};
    float m[2][4];
    #pragma unroll
    for (int hf = 0; hf < 2; ++hf)
        #pragma unroll
        for (int r = 0; r < 4; ++r) m[hf][r] = -1e30f;

    for (int k0 = 0; k0 < Sc; k0 += TK) {
        __syncthreads();                       // prev PV done: PsKs/Vs free
        #pragma unroll
        for (int u = 0; u < 2; ++u) {
            const int idx = t + u * 256;
            const int r = idx >> 3, cc = (idx & 7) * 8;
            *reinterpret_cast<uint4*>(&PsKs[r][cc]) =
                *reinterpret_cast<const uint4*>(Khi + kbase + (size_t)(k0 + r) * DKc + cc);
            *reinterpret_cast<uint4*>(&PsKs[64 + r][cc]) =
                *reinterpret_cast<const uint4*>(Klo + kbase + (size_t)(k0 + r) * DKc + cc);
            *reinterpret_cast<uint4*>(&Vs[r][cc]) =
                *reinterpret_cast<const uint4*>(Vtg + vbase + (size_t)r * Sc + k0 + cc);
        }
        if (t < TK) mk[t] = mb[k0 + t];
        __syncthreads();

        // ---- QK^T (both halves share the K fragments) -------------------
        float sc[2][4][4];
        #pragma unroll
        for (int n = 0; n < 4; ++n) {
            const bf16x8 kh0 = *reinterpret_cast<const bf16x8*>(&PsKs[n * 16 + li][lg * 8]);
            const bf16x8 kh1 = *reinterpret_cast<const bf16x8*>(&PsKs[n * 16 + li][32 + lg * 8]);
            const bf16x8 kl0 = *reinterpret_cast<const bf16x8*>(&PsKs[64 + n * 16 + li][lg * 8]);
            const bf16x8 kl1 = *reinterpret_cast<const bf16x8*>(&PsKs[64 + n * 16 + li][32 + lg * 8]);
            const float mz = mk[n * 16 + li] ? 0.0f : INF2;
            #pragma unroll
            for (int hf = 0; hf < 2; ++hf) {
                f32x4 a = {0, 0, 0, 0};
                a = __builtin_amdgcn_mfma_f32_16x16x32_bf16(qh[hf][0], kh0, a, 0, 0, 0);
                a = __builtin_amdgcn_mfma_f32_16x16x32_bf16(qh[hf][1], kh1, a, 0, 0, 0);
                a = __builtin_amdgcn_mfma_f32_16x16x32_bf16(qh[hf][0], kl0, a, 0, 0, 0);
                a = __builtin_amdgcn_mfma_f32_16x16x32_bf16(qh[hf][1], kl1, a, 0, 0, 0);
                a = __builtin_amdgcn_mfma_f32_16x16x32_bf16(ql[hf][0], kh0, a, 0, 0, 0);
                a = __builtin_amdgcn_mfma_f32_16x16x32_bf16(ql[hf][1], kh1, a, 0, 0, 0);
                #pragma unroll
                for (int r = 0; r < 4; ++r) sc[hf][n][r] = a[r] - mz;
            }
        }
        __syncthreads();                       // all K reads done -> Ps may overwrite

        // ---- row max (shfl over 16 li-lanes), exp2, pack P --------------
        float mx[2][4], rs[2][4];
        #pragma unroll
        for (int hf = 0; hf < 2; ++hf)
            #pragma unroll
            for (int r = 0; r < 4; ++r)
                mx[hf][r] = fmaxf(fmaxf(sc[hf][0][r], sc[hf][1][r]),
                                  fmaxf(sc[hf][2][r], sc[hf][3][r]));
        #pragma unroll
        for (int o = 1; o < 16; o <<= 1)
            #pragma unroll
            for (int hf = 0; hf < 2; ++hf)
                #pragma unroll
                for (int r = 0; r < 4; ++r)
                    mx[hf][r] = fmaxf(mx[hf][r], __shfl_xor(mx[hf][r], o));
        #pragma unroll
        for (int hf = 0; hf < 2; ++hf)
            #pragma unroll
            for (int r = 0; r < 4; ++r) {
                const float mn = fmaxf(m[hf][r], mx[hf][r]);
                rs[hf][r] = exp2f(m[hf][r] - mn);
                m[hf][r]  = mn;
            }
        // P values for keys {li,16+li,32+li,48+li} -> packed cols li*4+{0..3}
        #pragma unroll
        for (int hf = 0; hf < 2; ++hf)
            #pragma unroll
            for (int r = 0; r < 4; ++r) {
                const float p0 = exp2f(sc[hf][0][r] - m[hf][r]);
                const float p1 = exp2f(sc[hf][1][r] - m[hf][r]);
                const float p2 = exp2f(sc[hf][2][r] - m[hf][r]);
                const float p3 = exp2f(sc[hf][3][r] - m[hf][r]);
                uint2 w;
                w.x = pk_bf16(p0, p1);
                w.y = pk_bf16(p2, p3);
                *reinterpret_cast<uint2*>(&PsKs[wave * 32 + hf * 16 + lg * 4 + r][li * 4]) = w;
            }

        // rescale all accumulators (incl. the l-tile dt=4)
        #pragma unroll
        for (int hf = 0; hf < 2; ++hf)
            #pragma unroll
            for (int dt = 0; dt < 5; ++dt)
                #pragma unroll
                for (int r = 0; r < 4; ++r)
                    accO[hf][dt][r] *= rs[hf][r];

        // ---- PV (wave-local Ps; V cols in same col' order) --------------
        #pragma unroll
        for (int c = 0; c < 2; ++c) {
            bf16x8 pa[2];
            #pragma unroll
            for (int hf = 0; hf < 2; ++hf)
                pa[hf] = *reinterpret_cast<const bf16x8*>(&PsKs[wave * 32 + hf * 16 + li][c * 32 + lg * 8]);
            #pragma unroll
            for (int dt = 0; dt < 5; ++dt) {
                const bf16x8 vb = *reinterpret_cast<const bf16x8*>(&Vs[dt * 16 + li][c * 32 + lg * 8]);
                #pragma unroll
                for (int hf = 0; hf < 2; ++hf)
                    accO[hf][dt] = __builtin_amdgcn_mfma_f32_16x16x32_bf16(pa[hf], vb, accO[hf][dt], 0, 0, 0);
            }
        }
    }

    // l = col 0 of the dt=4 tile (li==0 lanes); out packed b64, col' layout
    #pragma unroll
    for (int hf = 0; hf < 2; ++hf) {
        float inv[4];
        #pragma unroll
        for (int r = 0; r < 4; ++r) {
            const float lb = __shfl(accO[hf][4][r], lane & 0x30);
            inv[r] = 1.0f / lb;
        }
        #pragma unroll
        for (int r = 0; r < 4; ++r) {
            const int q = q0 + wave * 32 + hf * 16 + lg * 4 + r;
            uint2 w;
            w.x = pk_bf16(accO[hf][0][r] * inv[r], accO[hf][1][r] * inv[r]);
            w.y = pk_bf16(accO[hf][2][r] * inv[r], accO[hf][3][r] * inv[r]);
            *reinterpret_cast<uint2*>(att + (size_t)(b * Sc + q) * Dc + h * DKc + li * 4) = w;
        }
    }
}

// ---------------------------------------------------------------------------
extern "C" void kernel_launch(void* const* d_in, const int* in_sizes, int n_in,
                              void* d_out, int out_size, void* d_ws, size_t ws_size,
                              hipStream_t stream) {
    const float* x    = (const float*)d_in[0];
    const void*  mraw = d_in[1];
    const float* WQ   = (const float*)d_in[2];
    const float* WK   = (const float*)d_in[3];
    const float* WV   = (const float*)d_in[4];
    const float* WO   = (const float*)d_in[5];
    float* out = (float*)d_out;

    int* mi = (int*)d_ws;
    const size_t SZ = (size_t)Mtot * Dc;
    const size_t WSZ = (size_t)Dc * Dc;
    unsigned short* xhi = (unsigned short*)((char*)d_ws + 32768);
    unsigned short* xlo = xhi + SZ;
    unsigned short* WQh = xlo + SZ;
    unsigned short* WQl = WQh + WSZ;
    unsigned short* WKh = WQh + 2 * WSZ;
    unsigned short* WKl = WQh + 3 * WSZ;
    unsigned short* WVh = WQh + 4 * WSZ;
    unsigned short* WOh = WQh + 5 * WSZ;
    unsigned short* Qhi = WQh + 6 * WSZ;
    unsigned short* Qlo = Qhi + SZ;
    unsigned short* Khi = Qhi + 2 * SZ;
    unsigned short* Klo = Qhi + 3 * SZ;
    unsigned short* Vt  = Qhi + 4 * SZ;
    unsigned short* att = xhi;     // alias: x split dead after projections

    mask_norm<<<1, 256, 0, stream>>>(mraw, mi);
    split_x<<<(int)(SZ / 1024), 256, 0, stream>>>(x, xhi, xlo);
    const dim3 gW(16, 16);
    split_wt<true , false><<<gW, 256, 0, stream>>>(WQ, WQh, WQl);
    split_wt<true , false><<<gW, 256, 0, stream>>>(WK, WKh, WKl);
    split_wt<false, false><<<gW, 256, 0, stream>>>(WV, WVh, nullptr);
    split_wt<false, true ><<<gW, 256, 0, stream>>>(WO, WOh, nullptr);

    const dim3 gG(Dc / 128, Mtot / 128);   // (8, 64)
    gemm_mfma<3, 0><<<gG, 256, 0, stream>>>(xhi, xlo, WQh, WQl, nullptr, SC2, Qhi, Qlo, nullptr);
    gemm_mfma<3, 0><<<gG, 256, 0, stream>>>(xhi, xlo, WKh, WKl, nullptr, 1.0f, Khi, Klo, nullptr);
    gemm_mfma<1, 1><<<gG, 256, 0, stream>>>(xhi, nullptr, WVh, nullptr, nullptr, 1.0f, Vt, nullptr, nullptr);

    attn_mfma<<<dim3(1024), 256, 0, stream>>>(Qhi, Qlo, Khi, Klo, Vt, mi, att);

    gemm_mfma<1, 2><<<gG, 256, 0, stream>>>(att, nullptr, WOh, nullptr, mi, 1.0f, nullptr, nullptr, out);
}